// Round 6
// baseline (474.274 us; speedup 1.0000x reference)
//
#include <hip/hip_runtime.h>
#include <hip/hip_bf16.h>
#include <math.h>

#define Bn   4
#define Hh   56
#define Wn   56
#define Cn   256
#define NHn  8
#define HDn  32
#define Nn   3136
#define LLn  9
#define PLn  196
#define PWn  14
#define KTABn 2048
#define Mrows 12544

// cvt5 segment offsets (elements)
#define XCNT   3211264            // 12544*256
#define QWOFF  XCNT               // +65536
#define KVWOFF (QWOFF + 65536)    // +131072
#define SRWOFF (KVWOFF + 131072)  // +65536
#define PWOFF  (SRWOFF + 65536)   // +65536
#define TOTCVT (PWOFF + 65536)    // 3538944

typedef __attribute__((ext_vector_type(8))) short short8v;
typedef __attribute__((ext_vector_type(4))) float float4v;

__device__ __forceinline__ unsigned short f2b(float f) {
  __hip_bfloat16 h = __float2bfloat16(f);
  return *(unsigned short*)&h;
}
__device__ __forceinline__ float b2f(unsigned short u) {
  union { unsigned int i; float f; } x; x.i = ((unsigned int)u) << 16; return x.f;
}

// ---------------------------------------------------------------------------
// Convert x + q_w + kv_w + sr_w + proj_w to one contiguous bf16 area.
// ---------------------------------------------------------------------------
__launch_bounds__(256)
__global__ void cvt5(const float* __restrict__ x, const float* __restrict__ qw,
                     const float* __restrict__ kvw, const float* __restrict__ srw,
                     const float* __restrict__ pw, unsigned short* __restrict__ dst)
{
  const int i = (blockIdx.x * 256 + threadIdx.x) * 4;
  const float* src; int off;
  if      (i < XCNT)   { src = x;   off = 0; }
  else if (i < KVWOFF) { src = qw;  off = QWOFF; }
  else if (i < SRWOFF) { src = kvw; off = KVWOFF; }
  else if (i < PWOFF)  { src = srw; off = SRWOFF; }
  else                 { src = pw;  off = PWOFF; }
  const float4 v = *(const float4*)(src + (i - off));
  ushort4 o2;
  o2.x = f2b(v.x); o2.y = f2b(v.y); o2.z = f2b(v.z); o2.w = f2b(v.w);
  *(ushort4*)(dst + i) = o2;
}

// ---------------------------------------------------------------------------
// bf16 MFMA GEMM: C[M,Nc] = A[M,256](bf16) @ W[Nc,256](bf16)^T + bias
// MODE 0: bias=b0.  MODE 1 (QKVS): seg bias (q|kv|sr) + gelu on seg 3.
// ---------------------------------------------------------------------------
template <int MODE>
__launch_bounds__(256)
__global__ void mgemm(const unsigned short* __restrict__ A,
                      const unsigned short* __restrict__ Wb,
                      const float* __restrict__ b0, const float* __restrict__ b1,
                      const float* __restrict__ b2, float* __restrict__ C, int Nc)
{
  __shared__ unsigned short As[128 * 64];
  __shared__ unsigned short Bs[128 * 64];
  const int t = threadIdx.x;
  const int w = t >> 6, lane = t & 63;
  const int q = lane >> 4, ln = lane & 15;
  const int n0 = blockIdx.x * 128, m0 = blockIdx.y * 128;
  const int wm = (w >> 1) * 64, wn = (w & 1) * 64;

  float4v acc[4][4];
  #pragma unroll
  for (int mt = 0; mt < 4; ++mt)
    #pragma unroll
    for (int nt = 0; nt < 4; ++nt)
      acc[mt][nt] = (float4v){0.f, 0.f, 0.f, 0.f};

  for (int k0 = 0; k0 < 256; k0 += 64) {
    #pragma unroll
    for (int j = 0; j < 4; ++j) {
      const int u = t + 256 * j;
      const int r = u >> 3, cg = u & 7;
      const int cs = cg ^ (r & 7);
      const uint4 av = *(const uint4*)(A  + (size_t)(m0 + r) * 256 + k0 + cg * 8);
      *(uint4*)(As + r * 64 + cs * 8) = av;
      const uint4 bv = *(const uint4*)(Wb + (size_t)(n0 + r) * 256 + k0 + cg * 8);
      *(uint4*)(Bs + r * 64 + cs * 8) = bv;
    }
    __syncthreads();
    #pragma unroll
    for (int kk = 0; kk < 2; ++kk) {
      short8v af[4], bfr[4];
      const int cg = kk * 4 + q;
      #pragma unroll
      for (int mt = 0; mt < 4; ++mt) {
        const int r = wm + mt * 16 + ln;
        af[mt] = *(const short8v*)(As + r * 64 + (cg ^ (r & 7)) * 8);
      }
      #pragma unroll
      for (int nt = 0; nt < 4; ++nt) {
        const int r = wn + nt * 16 + ln;
        bfr[nt] = *(const short8v*)(Bs + r * 64 + (cg ^ (r & 7)) * 8);
      }
      #pragma unroll
      for (int mt = 0; mt < 4; ++mt)
        #pragma unroll
        for (int nt = 0; nt < 4; ++nt)
          acc[mt][nt] = __builtin_amdgcn_mfma_f32_16x16x32_bf16(af[mt], bfr[nt], acc[mt][nt], 0, 0, 0);
    }
    __syncthreads();
  }

  #pragma unroll
  for (int nt = 0; nt < 4; ++nt) {
    const int col = n0 + wn + nt * 16 + ln;
    float bias;
    if constexpr (MODE == 0) bias = b0[col];
    else {
      const int seg = col >> 8;
      bias = (seg == 0) ? b0[col] : (seg == 3 ? b2[col - 768] : b1[col - 256]);
    }
    #pragma unroll
    for (int mt = 0; mt < 4; ++mt) {
      #pragma unroll
      for (int r = 0; r < 4; ++r) {
        const int row = m0 + wm + mt * 16 + q * 4 + r;
        float v = acc[mt][nt][r] + bias;
        if constexpr (MODE == 1)
          if (col >= 768) v = 0.5f * v * (1.0f + erff(v * 0.70710678118654752f));
        C[(size_t)row * Nc + col] = v;
      }
    }
  }
}

// ---------------------------------------------------------------------------
// fp32 tiled GEMM (pool path only)
// ---------------------------------------------------------------------------
__launch_bounds__(256)
__global__ void gemm_k(const float* __restrict__ A, const float* __restrict__ W,
                       const float* __restrict__ bias, float* __restrict__ Co,
                       int Mr, int Nc, int K)
{
  __shared__ __align__(16) float As[16][64];
  __shared__ __align__(16) float Ws[16][64];
  const int t  = threadIdx.x;
  const int m0 = blockIdx.y * 64, n0 = blockIdx.x * 64;
  const int lm = t >> 2, lk = (t & 3) << 2;
  const int tx = t & 15, ty = t >> 4;
  float acc[4][4] = {};
  int arow = m0 + lm; if (arow >= Mr) arow = Mr - 1;
  const int wrow = n0 + lm;
  for (int k0 = 0; k0 < K; k0 += 16) {
    float4 av = *(const float4*)(A + (size_t)arow * K + k0 + lk);
    As[lk+0][lm] = av.x; As[lk+1][lm] = av.y; As[lk+2][lm] = av.z; As[lk+3][lm] = av.w;
    float4 wv = *(const float4*)(W + (size_t)wrow * K + k0 + lk);
    Ws[lk+0][lm] = wv.x; Ws[lk+1][lm] = wv.y; Ws[lk+2][lm] = wv.z; Ws[lk+3][lm] = wv.w;
    __syncthreads();
    #pragma unroll
    for (int k = 0; k < 16; ++k) {
      float4 a = *(const float4*)&As[k][ty << 2];
      float4 w = *(const float4*)&Ws[k][tx << 2];
      acc[0][0] += a.x*w.x; acc[0][1] += a.x*w.y; acc[0][2] += a.x*w.z; acc[0][3] += a.x*w.w;
      acc[1][0] += a.y*w.x; acc[1][1] += a.y*w.y; acc[1][2] += a.y*w.z; acc[1][3] += a.y*w.w;
      acc[2][0] += a.z*w.x; acc[2][1] += a.z*w.y; acc[2][2] += a.z*w.z; acc[2][3] += a.z*w.w;
      acc[3][0] += a.w*w.x; acc[3][1] += a.w*w.y; acc[3][2] += a.w*w.z; acc[3][3] += a.w*w.w;
    }
    __syncthreads();
  }
  #pragma unroll
  for (int i = 0; i < 4; ++i) {
    const int row = m0 + (ty << 2) + i;
    if (row >= Mr) continue;
    #pragma unroll
    for (int j = 0; j < 4; ++j) {
      const int col = n0 + (tx << 2) + j;
      Co[(size_t)row * Nc + col] = acc[i][j] + bias[col];
    }
  }
}

// ---------------------------------------------------------------------------
// Per-head L2 norm: q (fused cols 0..255) -> q_scaled; k (256..511) in place.
// ---------------------------------------------------------------------------
__launch_bounds__(256)
__global__ void norm_qk2(float* __restrict__ fused, float* __restrict__ qsb,
                         const float* __restrict__ sls, const float* __restrict__ qe,
                         const float* __restrict__ temp)
{
  const int row = blockIdx.x;            // b*Nn + n
  const int c = threadIdx.x;
  const int h = c >> 5;
  const int n = row % Nn;
  float* f = fused + (size_t)row * 1024;
  float qv = f[c];
  float ss = qv * qv;
  #pragma unroll
  for (int m = 16; m >= 1; m >>= 1) ss += __shfl_xor(ss, m);
  const float qn = qv / fmaxf(sqrtf(ss), 1e-12f);
  const float spt = log1pf(expf(temp[h]));
  qsb[(size_t)row * Cn + c] = (qn + qe[c]) * spt * sls[n];
  float kval = f[256 + c];
  float ks = kval * kval;
  #pragma unroll
  for (int m = 16; m >= 1; m >>= 1) ks += __shfl_xor(ks, m);
  f[256 + c] = kval / fmaxf(sqrtf(ks), 1e-12f);
}

// ---------------------------------------------------------------------------
// 4x4 average pool of gelu'd sr (fused cols 768..1023) + LayerNorm over C
// ---------------------------------------------------------------------------
__launch_bounds__(256)
__global__ void pool_ln_k(const float* __restrict__ fused, float* __restrict__ pln,
                          const float* __restrict__ g, const float* __restrict__ bb)
{
  const int blk = blockIdx.x;
  const int b = blk / PLn, pc = blk % PLn;
  const int pi = pc / PWn, pj = pc % PWn;
  const int c = threadIdx.x;
  float s = 0.f;
  #pragma unroll
  for (int r = 0; r < 4; ++r)
    #pragma unroll
    for (int cc = 0; cc < 4; ++cc) {
      const int n = (pi*4 + r) * Wn + pj*4 + cc;
      s += fused[((size_t)b * Nn + n) * 1024 + 768 + c];
    }
  s *= (1.f/16.f);
  float sum = s, sq = s*s;
  #pragma unroll
  for (int m = 32; m >= 1; m >>= 1) { sum += __shfl_xor(sum, m); sq += __shfl_xor(sq, m); }
  __shared__ float sm[8];
  const int lane = c & 63, wid = c >> 6;
  if (lane == 0) { sm[wid] = sum; sm[4+wid] = sq; }
  __syncthreads();
  const float tot  = sm[0]+sm[1]+sm[2]+sm[3];
  const float totq = sm[4]+sm[5]+sm[6]+sm[7];
  const float mu  = tot * (1.f/256.f);
  const float var = totq * (1.f/256.f) - mu*mu;
  pln[(size_t)blk * Cn + c] = (s - mu) / sqrtf(var + 1e-5f) * g[c] + bb[c];
}

// ---------------------------------------------------------------------------
// split kvp -> k_pool (L2-normed per head) / v_pool in (b,h,m,d) layout
// ---------------------------------------------------------------------------
__launch_bounds__(256)
__global__ void pool_split_k(const float* __restrict__ kvp, float* __restrict__ kpn,
                             float* __restrict__ vpl)
{
  const int bm = blockIdx.x;
  const int b = bm / PLn, m = bm % PLn;
  const int c = threadIdx.x;
  const int h = c >> 5, d = c & 31;
  float kval = kvp[(size_t)bm * 512 + c];
  float ss = kval * kval;
  #pragma unroll
  for (int mm = 16; mm >= 1; mm >>= 1) ss += __shfl_xor(ss, mm);
  const size_t oidx = (((size_t)b * NHn + h) * PLn + m) * HDn + d;
  kpn[oidx] = kval / fmaxf(sqrtf(ss), 1e-12f);
  vpl[oidx] = kvp[(size_t)bm * 512 + 256 + c];
}

// ---------------------------------------------------------------------------
// CPB MLP: tab[r][h] = relu(rct[r]@w1^T + b1) @ w2^T + b2   (2048 x 8)
// ---------------------------------------------------------------------------
__launch_bounds__(64)
__global__ void cpb_k(const float* __restrict__ rct, const float* __restrict__ w1,
                      const float* __restrict__ b1, const float* __restrict__ w2,
                      const float* __restrict__ b2, float* __restrict__ tab)
{
  const int r = blockIdx.x, t = threadIdx.x;
  const float c0 = rct[r*2], c1 = rct[r*2+1];
  float part[8] = {};
  #pragma unroll
  for (int jj = 0; jj < 8; ++jj) {
    const int j = t * 8 + jj;
    float hv = fmaxf(c0 * w1[j*2] + c1 * w1[j*2+1] + b1[j], 0.f);
    #pragma unroll
    for (int h = 0; h < 8; ++h) part[h] += hv * w2[h*512 + j];
  }
  #pragma unroll
  for (int h = 0; h < 8; ++h)
    for (int mm = 32; mm >= 1; mm >>= 1) part[h] += __shfl_xor(part[h], mm);
  if (t < 8) tab[r*8 + t] = part[t] + b2[t];
}

// ---------------------------------------------------------------------------
// global max over tab and rpb -> scal[0]
// ---------------------------------------------------------------------------
__launch_bounds__(256)
__global__ void redmax_k(const float* __restrict__ tab, const float* __restrict__ rpb,
                         float* __restrict__ scal)
{
  float mx = -1e30f;
  for (int i = threadIdx.x; i < KTABn*NHn; i += 256) mx = fmaxf(mx, tab[i]);
  if (threadIdx.x < NHn*LLn) mx = fmaxf(mx, rpb[threadIdx.x]);
  #pragma unroll
  for (int m = 32; m >= 1; m >>= 1) mx = fmaxf(mx, __shfl_xor(mx, m));
  __shared__ float sm[4];
  if ((threadIdx.x & 63) == 0) sm[threadIdx.x >> 6] = mx;
  __syncthreads();
  if (threadIdx.x == 0) scal[0] = fmaxf(fmaxf(sm[0], sm[1]), fmaxf(sm[2], sm[3]));
}

// ---------------------------------------------------------------------------
// Gather pool bias: bias2[h][m][n] = bf16(tab[rpi[n*PL+m]][h]); writes coalesced
// ---------------------------------------------------------------------------
__launch_bounds__(256)
__global__ void bias_g_k(const int* __restrict__ rpi, const float* __restrict__ tab,
                         unsigned short* __restrict__ bias2)
{
  const int tid = blockIdx.x * 256 + threadIdx.x;   // m*Nn + n ; grid exact
  const int m = tid / Nn, n = tid % Nn;
  const int idx = rpi[(size_t)n * PLn + m];
  #pragma unroll
  for (int h = 0; h < NHn; ++h)
    bias2[((size_t)h * PLn + m) * Nn + n] = f2b(tab[(size_t)idx * NHn + h]);
}

// ---------------------------------------------------------------------------
// attn5: block = 4 waves over the SAME 64 n; each wave owns 49 pool keys
// (wave-uniform k/v loads) + 2-3 local keys. Fixed-M softmax => partials are
// additive; combined via LDS at the end. qn reconstructed from qs.
// ---------------------------------------------------------------------------
__launch_bounds__(256, 4)
__global__ void attn5(const float* __restrict__ qs_, const float* __restrict__ slsp,
                      const float* __restrict__ temp, const float* __restrict__ qe,
                      const float* __restrict__ lt, const float* __restrict__ lb,
                      const float* __restrict__ fused, const float* __restrict__ kpn,
                      const float* __restrict__ vpl, const unsigned short* __restrict__ bias2,
                      const float* __restrict__ rpb, const float* __restrict__ scal,
                      unsigned short* __restrict__ outp)
{
  __shared__ float red[4 * 64 * 33];        // 33.8 KB, reused for two phases
  __shared__ float lt_s[HDn * LLn];
  __shared__ float qe_s[HDn];
  __shared__ float lb_s[LLn], rpb_s[LLn];
  const int t = threadIdx.x;
  const int w = t >> 6, lane = t & 63;
  const int tile = blockIdx.x, h = blockIdx.y, b = blockIdx.z;
  const int n = tile * 64 + lane;           // 49*64 == 3136 exact
  const int bh = b * NHn + h;

  for (int i = t; i < HDn * LLn; i += 256) lt_s[i] = lt[h * HDn * LLn + i];  // FIX: 288 > 256
  if (t < HDn) qe_s[t] = qe[h * HDn + t];
  if (t < LLn) { lb_s[t] = lb[h * LLn + t]; rpb_s[t] = rpb[h * LLn + t]; }
  __syncthreads();

  const size_t rowq = ((size_t)b * Nn + n) * Cn + h * HDn;
  float qs[HDn];
  #pragma unroll
  for (int dq = 0; dq < 8; ++dq) {
    float4 s4 = ((const float4*)(qs_ + rowq))[dq];
    qs[dq*4]=s4.x; qs[dq*4+1]=s4.y; qs[dq*4+2]=s4.z; qs[dq*4+3]=s4.w;
  }
  float ssq = 0.f;
  #pragma unroll
  for (int d = 0; d < HDn; ++d) ssq += qs[d] * qs[d];
  const float M = sqrtf(ssq) + scal[0];

  float acc[HDn];
  #pragma unroll
  for (int d = 0; d < HDn; ++d) acc[d] = 0.f;
  float l_run = 0.f;

  const float* kbase = kpn + (size_t)bh * PLn * HDn;
  const float* vbase = vpl + (size_t)bh * PLn * HDn;
  const unsigned short* bptr = bias2 + (size_t)h * PLn * Nn + n;

  const int m0 = w * 49;
  #pragma unroll 2
  for (int i = 0; i < 49; ++i) {
    const int m = m0 + i;
    const float bias = b2f(bptr[(size_t)m * Nn]);
    const float4* k4 = (const float4*)(kbase + m * HDn);   // wave-uniform
    float p0=0,p1=0,p2=0,p3=0;
    #pragma unroll
    for (int dq = 0; dq < 8; ++dq) {
      float4 kk = k4[dq];
      p0 += qs[dq*4+0]*kk.x; p1 += qs[dq*4+1]*kk.y;
      p2 += qs[dq*4+2]*kk.z; p3 += qs[dq*4+3]*kk.w;
    }
    const float p = __expf(((p0+p1)+(p2+p3) + bias) - M);
    l_run += p;
    const float4* v4 = (const float4*)(vbase + m * HDn);   // wave-uniform
    #pragma unroll
    for (int dq = 0; dq < 8; ++dq) {
      float4 vv = v4[dq];
      const int d = dq*4;
      acc[d] += p*vv.x; acc[d+1] += p*vv.y; acc[d+2] += p*vv.z; acc[d+3] += p*vv.w;
    }
  }

  // local part: wave w handles lc = w, w+4, w+8
  float ext[HDn];
  #pragma unroll
  for (int d = 0; d < HDn; ++d) ext[d] = 0.f;
  const float spt = log1pf(__expf(temp[h]));
  const float inv_qs = 1.f / (spt * slsp[n]);
  const int pi = n / Wn, pj = n % Wn;
  for (int lc = w; lc < LLn; lc += 4) {
    const int ii = pi + lc/3 - 1, jj = pj + (lc%3) - 1;
    if (ii < 0 || ii >= Hh || jj < 0 || jj >= Wn) continue;
    const int nb2 = ii * Wn + jj;
    float e = lb_s[lc];
    #pragma unroll
    for (int d = 0; d < HDn; ++d) e += (qs[d]*inv_qs - qe_s[d]) * lt_s[d*LLn + lc];
    const float* kr = fused + ((size_t)b * Nn + nb2) * 1024 + 256 + h * HDn;
    float p0=0,p1=0,p2=0,p3=0;
    #pragma unroll
    for (int dq = 0; dq < 8; ++dq) {
      float4 kk = ((const float4*)kr)[dq];
      p0 += qs[dq*4+0]*kk.x; p1 += qs[dq*4+1]*kk.y;
      p2 += qs[dq*4+2]*kk.z; p3 += qs[dq*4+3]*kk.w;
    }
    const float p = __expf(((p0+p1)+(p2+p3) + rpb_s[lc]) - M);
    l_run += p;
    #pragma unroll
    for (int dq = 0; dq < 8; ++dq) {              // reload v (keeps VGPR low)
      float4 vv = ((const float4*)(kr + Cn))[dq];
      const int d = dq*4;
      acc[d] += p*vv.x; acc[d+1] += p*vv.y; acc[d+2] += p*vv.z; acc[d+3] += p*vv.w;
      ext[d] += e*vv.x; ext[d+1] += e*vv.y; ext[d+2] += e*vv.z; ext[d+3] += e*vv.w;
    }
  }

  // phase A: acc + l_run
  float* myred = red + (w * 64 + lane) * 33;
  #pragma unroll
  for (int d = 0; d < HDn; ++d) myred[d] = acc[d];
  myred[32] = l_run;
  __syncthreads();
  const int n2 = t >> 2, dg = t & 3;
  float o[8], l_tot;
  {
    const float* r0 = red + n2 * 33, *r1 = r0 + 64*33, *r2 = r1 + 64*33, *r3 = r2 + 64*33;
    l_tot = r0[32] + r1[32] + r2[32] + r3[32];
    #pragma unroll
    for (int j = 0; j < 8; ++j)
      o[j] = r0[dg*8+j] + r1[dg*8+j] + r2[dg*8+j] + r3[dg*8+j];
  }
  __syncthreads();
  // phase B: ext
  #pragma unroll
  for (int d = 0; d < HDn; ++d) myred[d] = ext[d];
  __syncthreads();
  float et[8];
  {
    const float* r0 = red + n2 * 33, *r1 = r0 + 64*33, *r2 = r1 + 64*33, *r3 = r2 + 64*33;
    #pragma unroll
    for (int j = 0; j < 8; ++j)
      et[j] = r0[dg*8+j] + r1[dg*8+j] + r2[dg*8+j] + r3[dg*8+j];
  }
  const float invl = 1.f / l_tot;
  uint4 u;
  u.x = f2b(o[0]*invl+et[0]) | ((unsigned int)f2b(o[1]*invl+et[1]) << 16);
  u.y = f2b(o[2]*invl+et[2]) | ((unsigned int)f2b(o[3]*invl+et[3]) << 16);
  u.z = f2b(o[4]*invl+et[4]) | ((unsigned int)f2b(o[5]*invl+et[5]) << 16);
  u.w = f2b(o[6]*invl+et[6]) | ((unsigned int)f2b(o[7]*invl+et[7]) << 16);
  *(uint4*)(outp + ((size_t)b * Nn + tile*64 + n2) * Cn + h * HDn + dg * 8) = u;
}

// ---------------------------------------------------------------------------
extern "C" void kernel_launch(void* const* d_in, const int* in_sizes, int n_in,
                              void* d_out, int out_size, void* d_ws, size_t ws_size,
                              hipStream_t stream)
{
  const float* x    = (const float*)d_in[0];
  const int*   rpi  = (const int*)d_in[3];
  const float* rct  = (const float*)d_in[4];
  const float* sls  = (const float*)d_in[5];
  const float* q_w  = (const float*)d_in[7];
  const float* q_b  = (const float*)d_in[8];
  const float* kv_w = (const float*)d_in[9];
  const float* kv_b = (const float*)d_in[10];
  const float* sr_w = (const float*)d_in[11];
  const float* sr_b = (const float*)d_in[12];
  const float* ng   = (const float*)d_in[13];
  const float* nbta = (const float*)d_in[14];
  const float* c1w  = (const float*)d_in[15];
  const float* c1b  = (const float*)d_in[16];
  const float* c2w  = (const float*)d_in[17];
  const float* c2b  = (const float*)d_in[18];
  const float* temp = (const float*)d_in[19];
  const float* qe   = (const float*)d_in[20];
  const float* rpb  = (const float*)d_in[21];
  const float* lt   = (const float*)d_in[22];
  const float* lb   = (const float*)d_in[23];
  const float* pw   = (const float*)d_in[24];
  const float* pb   = (const float*)d_in[25];

  float* ws = (float*)d_ws;
  size_t o = 0;
  unsigned short* bf = (unsigned short*)(ws + o); o += TOTCVT / 2;
  float* fused = ws + o;  o += (size_t)Mrows * 1024;
  float* qsb   = ws + o;  o += (size_t)Mrows * Cn;
  float* pln   = ws + o;  o += (size_t)Bn * PLn * Cn;
  float* kvp   = ws + o;  o += (size_t)Bn * PLn * 2 * Cn;
  float* kpn   = ws + o;  o += (size_t)Bn * PLn * Cn;
  float* vpl   = ws + o;  o += (size_t)Bn * PLn * Cn;
  float* tab   = ws + o;  o += (size_t)KTABn * NHn;
  float* scal  = ws + o;  o += 8;
  unsigned short* bias2 = (unsigned short*)(ws + o); o += (size_t)NHn * Nn * PLn / 2;
  unsigned short* outp  = (unsigned short*)(ws + o); o += (size_t)Mrows * Cn / 2;

  const unsigned short* xbf   = bf;
  const unsigned short* qkvsw = bf + QWOFF;
  const unsigned short* pwbf  = bf + PWOFF;

  cvt5<<<TOTCVT/1024, 256, 0, stream>>>(x, q_w, kv_w, sr_w, pw, bf);
  mgemm<1><<<dim3(8, 98), 256, 0, stream>>>(xbf, qkvsw, q_b, kv_b, sr_b, fused, 1024);
  norm_qk2<<<Mrows, 256, 0, stream>>>(fused, qsb, sls, qe, temp);
  pool_ln_k<<<Bn*PLn, 256, 0, stream>>>(fused, pln, ng, nbta);
  gemm_k<<<dim3(8, 13), 256, 0, stream>>>(pln, kv_w, kv_b, kvp, Bn*PLn, 512, 256);
  pool_split_k<<<Bn*PLn, 256, 0, stream>>>(kvp, kpn, vpl);
  cpb_k<<<KTABn, 64, 0, stream>>>(rct, c1w, c1b, c2w, c2b, tab);
  redmax_k<<<1, 256, 0, stream>>>(tab, rpb, scal);
  bias_g_k<<<(Nn*PLn)/256, 256, 0, stream>>>(rpi, tab, bias2);
  attn5<<<dim3(49, NHn, Bn), 256, 0, stream>>>(qsb, sls, temp, qe, lt, lb, fused,
                                               kpn, vpl, bias2, rpb, scal, outp);
  mgemm<0><<<dim3(2, 98), 256, 0, stream>>>(outp, pwbf, pb, pb, pb, (float*)d_out, 256);
}

// Round 7
// 401.284 us; speedup vs baseline: 1.1819x; 1.1819x over previous
//
#include <hip/hip_runtime.h>
#include <hip/hip_bf16.h>
#include <math.h>

#define Bn   4
#define Hh   56
#define Wn   56
#define Cn   256
#define NHn  8
#define HDn  32
#define Nn   3136
#define LLn  9
#define PLn  196
#define PWn  14
#define KTABn 2048
#define Mrows 12544

// cvt5 segment offsets (elements)
#define XCNT   3211264            // 12544*256
#define QWOFF  XCNT               // +65536
#define KVWOFF (QWOFF + 65536)    // +131072
#define SRWOFF (KVWOFF + 131072)  // +65536
#define PWOFF  (SRWOFF + 65536)   // +65536
#define TOTCVT (PWOFF + 65536)    // 3538944

typedef __attribute__((ext_vector_type(8))) short short8v;
typedef __attribute__((ext_vector_type(4))) float float4v;

__device__ __forceinline__ unsigned short f2b(float f) {
  __hip_bfloat16 h = __float2bfloat16(f);
  return *(unsigned short*)&h;
}
__device__ __forceinline__ float b2f(unsigned short u) {
  union { unsigned int i; float f; } x; x.i = ((unsigned int)u) << 16; return x.f;
}

// ---------------------------------------------------------------------------
// Convert x + q_w + kv_w + sr_w + proj_w to one contiguous bf16 area.
// ---------------------------------------------------------------------------
__launch_bounds__(256)
__global__ void cvt5(const float* __restrict__ x, const float* __restrict__ qw,
                     const float* __restrict__ kvw, const float* __restrict__ srw,
                     const float* __restrict__ pw, unsigned short* __restrict__ dst)
{
  const int i = (blockIdx.x * 256 + threadIdx.x) * 4;
  const float* src; int off;
  if      (i < XCNT)   { src = x;   off = 0; }
  else if (i < KVWOFF) { src = qw;  off = QWOFF; }
  else if (i < SRWOFF) { src = kvw; off = KVWOFF; }
  else if (i < PWOFF)  { src = srw; off = SRWOFF; }
  else                 { src = pw;  off = PWOFF; }
  const float4 v = *(const float4*)(src + (i - off));
  ushort4 o2;
  o2.x = f2b(v.x); o2.y = f2b(v.y); o2.z = f2b(v.z); o2.w = f2b(v.w);
  *(ushort4*)(dst + i) = o2;
}

// ---------------------------------------------------------------------------
// bf16 MFMA GEMM: C[M,Nc] = A[M,256](bf16) @ W[Nc,256](bf16)^T + bias
// MODE 0: bias=b0.  MODE 1 (QKVS): seg bias (q|kv|sr) + gelu on seg 3.
// ---------------------------------------------------------------------------
template <int MODE>
__launch_bounds__(256)
__global__ void mgemm(const unsigned short* __restrict__ A,
                      const unsigned short* __restrict__ Wb,
                      const float* __restrict__ b0, const float* __restrict__ b1,
                      const float* __restrict__ b2, float* __restrict__ C, int Nc)
{
  __shared__ unsigned short As[128 * 64];
  __shared__ unsigned short Bs[128 * 64];
  const int t = threadIdx.x;
  const int w = t >> 6, lane = t & 63;
  const int q = lane >> 4, ln = lane & 15;
  const int n0 = blockIdx.x * 128, m0 = blockIdx.y * 128;
  const int wm = (w >> 1) * 64, wn = (w & 1) * 64;

  float4v acc[4][4];
  #pragma unroll
  for (int mt = 0; mt < 4; ++mt)
    #pragma unroll
    for (int nt = 0; nt < 4; ++nt)
      acc[mt][nt] = (float4v){0.f, 0.f, 0.f, 0.f};

  for (int k0 = 0; k0 < 256; k0 += 64) {
    #pragma unroll
    for (int j = 0; j < 4; ++j) {
      const int u = t + 256 * j;
      const int r = u >> 3, cg = u & 7;
      const int cs = cg ^ (r & 7);
      const uint4 av = *(const uint4*)(A  + (size_t)(m0 + r) * 256 + k0 + cg * 8);
      *(uint4*)(As + r * 64 + cs * 8) = av;
      const uint4 bv = *(const uint4*)(Wb + (size_t)(n0 + r) * 256 + k0 + cg * 8);
      *(uint4*)(Bs + r * 64 + cs * 8) = bv;
    }
    __syncthreads();
    #pragma unroll
    for (int kk = 0; kk < 2; ++kk) {
      short8v af[4], bfr[4];
      const int cg = kk * 4 + q;
      #pragma unroll
      for (int mt = 0; mt < 4; ++mt) {
        const int r = wm + mt * 16 + ln;
        af[mt] = *(const short8v*)(As + r * 64 + (cg ^ (r & 7)) * 8);
      }
      #pragma unroll
      for (int nt = 0; nt < 4; ++nt) {
        const int r = wn + nt * 16 + ln;
        bfr[nt] = *(const short8v*)(Bs + r * 64 + (cg ^ (r & 7)) * 8);
      }
      #pragma unroll
      for (int mt = 0; mt < 4; ++mt)
        #pragma unroll
        for (int nt = 0; nt < 4; ++nt)
          acc[mt][nt] = __builtin_amdgcn_mfma_f32_16x16x32_bf16(af[mt], bfr[nt], acc[mt][nt], 0, 0, 0);
    }
    __syncthreads();
  }

  #pragma unroll
  for (int nt = 0; nt < 4; ++nt) {
    const int col = n0 + wn + nt * 16 + ln;
    float bias;
    if constexpr (MODE == 0) bias = b0[col];
    else {
      const int seg = col >> 8;
      bias = (seg == 0) ? b0[col] : (seg == 3 ? b2[col - 768] : b1[col - 256]);
    }
    #pragma unroll
    for (int mt = 0; mt < 4; ++mt) {
      #pragma unroll
      for (int r = 0; r < 4; ++r) {
        const int row = m0 + wm + mt * 16 + q * 4 + r;
        float v = acc[mt][nt][r] + bias;
        if constexpr (MODE == 1)
          if (col >= 768) v = 0.5f * v * (1.0f + erff(v * 0.70710678118654752f));
        C[(size_t)row * Nc + col] = v;
      }
    }
  }
}

// ---------------------------------------------------------------------------
// fp32 tiled GEMM (pool path only)
// ---------------------------------------------------------------------------
__launch_bounds__(256)
__global__ void gemm_k(const float* __restrict__ A, const float* __restrict__ W,
                       const float* __restrict__ bias, float* __restrict__ Co,
                       int Mr, int Nc, int K)
{
  __shared__ __align__(16) float As[16][64];
  __shared__ __align__(16) float Ws[16][64];
  const int t  = threadIdx.x;
  const int m0 = blockIdx.y * 64, n0 = blockIdx.x * 64;
  const int lm = t >> 2, lk = (t & 3) << 2;
  const int tx = t & 15, ty = t >> 4;
  float acc[4][4] = {};
  int arow = m0 + lm; if (arow >= Mr) arow = Mr - 1;
  const int wrow = n0 + lm;
  for (int k0 = 0; k0 < K; k0 += 16) {
    float4 av = *(const float4*)(A + (size_t)arow * K + k0 + lk);
    As[lk+0][lm] = av.x; As[lk+1][lm] = av.y; As[lk+2][lm] = av.z; As[lk+3][lm] = av.w;
    float4 wv = *(const float4*)(W + (size_t)wrow * K + k0 + lk);
    Ws[lk+0][lm] = wv.x; Ws[lk+1][lm] = wv.y; Ws[lk+2][lm] = wv.z; Ws[lk+3][lm] = wv.w;
    __syncthreads();
    #pragma unroll
    for (int k = 0; k < 16; ++k) {
      float4 a = *(const float4*)&As[k][ty << 2];
      float4 w = *(const float4*)&Ws[k][tx << 2];
      acc[0][0] += a.x*w.x; acc[0][1] += a.x*w.y; acc[0][2] += a.x*w.z; acc[0][3] += a.x*w.w;
      acc[1][0] += a.y*w.x; acc[1][1] += a.y*w.y; acc[1][2] += a.y*w.z; acc[1][3] += a.y*w.w;
      acc[2][0] += a.z*w.x; acc[2][1] += a.z*w.y; acc[2][2] += a.z*w.z; acc[2][3] += a.z*w.w;
      acc[3][0] += a.w*w.x; acc[3][1] += a.w*w.y; acc[3][2] += a.w*w.z; acc[3][3] += a.w*w.w;
    }
    __syncthreads();
  }
  #pragma unroll
  for (int i = 0; i < 4; ++i) {
    const int row = m0 + (ty << 2) + i;
    if (row >= Mr) continue;
    #pragma unroll
    for (int j = 0; j < 4; ++j) {
      const int col = n0 + (tx << 2) + j;
      Co[(size_t)row * Nc + col] = acc[i][j] + bias[col];
    }
  }
}

// ---------------------------------------------------------------------------
// Per-head L2 norm: q (fused cols 0..255) -> q_scaled; k (256..511) in place.
// ---------------------------------------------------------------------------
__launch_bounds__(256)
__global__ void norm_qk2(float* __restrict__ fused, float* __restrict__ qsb,
                         const float* __restrict__ sls, const float* __restrict__ qe,
                         const float* __restrict__ temp)
{
  const int row = blockIdx.x;            // b*Nn + n
  const int c = threadIdx.x;
  const int h = c >> 5;
  const int n = row % Nn;
  float* f = fused + (size_t)row * 1024;
  float qv = f[c];
  float ss = qv * qv;
  #pragma unroll
  for (int m = 16; m >= 1; m >>= 1) ss += __shfl_xor(ss, m);
  const float qn = qv / fmaxf(sqrtf(ss), 1e-12f);
  const float spt = log1pf(expf(temp[h]));
  qsb[(size_t)row * Cn + c] = (qn + qe[c]) * spt * sls[n];
  float kval = f[256 + c];
  float ks = kval * kval;
  #pragma unroll
  for (int m = 16; m >= 1; m >>= 1) ks += __shfl_xor(ks, m);
  f[256 + c] = kval / fmaxf(sqrtf(ks), 1e-12f);
}

// ---------------------------------------------------------------------------
// 4x4 average pool of gelu'd sr (fused cols 768..1023) + LayerNorm over C
// ---------------------------------------------------------------------------
__launch_bounds__(256)
__global__ void pool_ln_k(const float* __restrict__ fused, float* __restrict__ pln,
                          const float* __restrict__ g, const float* __restrict__ bb)
{
  const int blk = blockIdx.x;
  const int b = blk / PLn, pc = blk % PLn;
  const int pi = pc / PWn, pj = pc % PWn;
  const int c = threadIdx.x;
  float s = 0.f;
  #pragma unroll
  for (int r = 0; r < 4; ++r)
    #pragma unroll
    for (int cc = 0; cc < 4; ++cc) {
      const int n = (pi*4 + r) * Wn + pj*4 + cc;
      s += fused[((size_t)b * Nn + n) * 1024 + 768 + c];
    }
  s *= (1.f/16.f);
  float sum = s, sq = s*s;
  #pragma unroll
  for (int m = 32; m >= 1; m >>= 1) { sum += __shfl_xor(sum, m); sq += __shfl_xor(sq, m); }
  __shared__ float sm[8];
  const int lane = c & 63, wid = c >> 6;
  if (lane == 0) { sm[wid] = sum; sm[4+wid] = sq; }
  __syncthreads();
  const float tot  = sm[0]+sm[1]+sm[2]+sm[3];
  const float totq = sm[4]+sm[5]+sm[6]+sm[7];
  const float mu  = tot * (1.f/256.f);
  const float var = totq * (1.f/256.f) - mu*mu;
  pln[(size_t)blk * Cn + c] = (s - mu) / sqrtf(var + 1e-5f) * g[c] + bb[c];
}

// ---------------------------------------------------------------------------
// split kvp -> k_pool (L2-normed per head) / v_pool in (b,h,m,d) layout
// ---------------------------------------------------------------------------
__launch_bounds__(256)
__global__ void pool_split_k(const float* __restrict__ kvp, float* __restrict__ kpn,
                             float* __restrict__ vpl)
{
  const int bm = blockIdx.x;
  const int b = bm / PLn, m = bm % PLn;
  const int c = threadIdx.x;
  const int h = c >> 5, d = c & 31;
  float kval = kvp[(size_t)bm * 512 + c];
  float ss = kval * kval;
  #pragma unroll
  for (int mm = 16; mm >= 1; mm >>= 1) ss += __shfl_xor(ss, mm);
  const size_t oidx = (((size_t)b * NHn + h) * PLn + m) * HDn + d;
  kpn[oidx] = kval / fmaxf(sqrtf(ss), 1e-12f);
  vpl[oidx] = kvp[(size_t)bm * 512 + 256 + c];
}

// ---------------------------------------------------------------------------
// CPB MLP: tab[r][h] = relu(rct[r]@w1^T + b1) @ w2^T + b2   (2048 x 8)
// ---------------------------------------------------------------------------
__launch_bounds__(64)
__global__ void cpb_k(const float* __restrict__ rct, const float* __restrict__ w1,
                      const float* __restrict__ b1, const float* __restrict__ w2,
                      const float* __restrict__ b2, float* __restrict__ tab)
{
  const int r = blockIdx.x, t = threadIdx.x;
  const float c0 = rct[r*2], c1 = rct[r*2+1];
  float part[8] = {};
  #pragma unroll
  for (int jj = 0; jj < 8; ++jj) {
    const int j = t * 8 + jj;
    float hv = fmaxf(c0 * w1[j*2] + c1 * w1[j*2+1] + b1[j], 0.f);
    #pragma unroll
    for (int h = 0; h < 8; ++h) part[h] += hv * w2[h*512 + j];
  }
  #pragma unroll
  for (int h = 0; h < 8; ++h)
    for (int mm = 32; mm >= 1; mm >>= 1) part[h] += __shfl_xor(part[h], mm);
  if (t < 8) tab[r*8 + t] = part[t] + b2[t];
}

// ---------------------------------------------------------------------------
// global max over tab and rpb -> scal[0]
// ---------------------------------------------------------------------------
__launch_bounds__(256)
__global__ void redmax_k(const float* __restrict__ tab, const float* __restrict__ rpb,
                         float* __restrict__ scal)
{
  float mx = -1e30f;
  for (int i = threadIdx.x; i < KTABn*NHn; i += 256) mx = fmaxf(mx, tab[i]);
  if (threadIdx.x < NHn*LLn) mx = fmaxf(mx, rpb[threadIdx.x]);
  #pragma unroll
  for (int m = 32; m >= 1; m >>= 1) mx = fmaxf(mx, __shfl_xor(mx, m));
  __shared__ float sm[4];
  if ((threadIdx.x & 63) == 0) sm[threadIdx.x >> 6] = mx;
  __syncthreads();
  if (threadIdx.x == 0) scal[0] = fmaxf(fmaxf(sm[0], sm[1]), fmaxf(sm[2], sm[3]));
}

// ---------------------------------------------------------------------------
// Gather pool bias: bias2[h][m][n] = bf16(tab[rpi[n*PL+m]][h]); writes coalesced
// ---------------------------------------------------------------------------
__launch_bounds__(256)
__global__ void bias_g_k(const int* __restrict__ rpi, const float* __restrict__ tab,
                         unsigned short* __restrict__ bias2)
{
  const int tid = blockIdx.x * 256 + threadIdx.x;   // m*Nn + n ; grid exact
  const int m = tid / Nn, n = tid % Nn;
  const int idx = rpi[(size_t)n * PLn + m];
  #pragma unroll
  for (int h = 0; h < NHn; ++h)
    bias2[((size_t)h * PLn + m) * Nn + n] = f2b(tab[(size_t)idx * NHn + h]);
}

// ---------------------------------------------------------------------------
// attn5: block = 4 waves over the SAME 64 n; each wave owns 49 pool keys
// (wave-uniform k/v loads) + 2-3 local keys. Fixed-M softmax => partials are
// additive; combined via LDS at the end. qn reconstructed from qs.
// __launch_bounds__(256,2): VGPR cap 256 — round-6's (256,4) capped at 128
// and spilled acc/ext to scratch (56 MB writes, 277us). LDS (35.3KB) still
// allows 4 blocks/CU if VGPRs land <=128 naturally; 3 blocks/CU at ~170.
// ---------------------------------------------------------------------------
__launch_bounds__(256, 2)
__global__ void attn5(const float* __restrict__ qs_, const float* __restrict__ slsp,
                      const float* __restrict__ temp, const float* __restrict__ qe,
                      const float* __restrict__ lt, const float* __restrict__ lb,
                      const float* __restrict__ fused, const float* __restrict__ kpn,
                      const float* __restrict__ vpl, const unsigned short* __restrict__ bias2,
                      const float* __restrict__ rpb, const float* __restrict__ scal,
                      unsigned short* __restrict__ outp)
{
  __shared__ float red[4 * 64 * 33];        // 33.8 KB, reused for two phases
  __shared__ float lt_s[HDn * LLn];
  __shared__ float qe_s[HDn];
  __shared__ float lb_s[LLn], rpb_s[LLn];
  const int t = threadIdx.x;
  const int w = t >> 6, lane = t & 63;
  const int tile = blockIdx.x, h = blockIdx.y, b = blockIdx.z;
  const int n = tile * 64 + lane;           // 49*64 == 3136 exact
  const int bh = b * NHn + h;

  for (int i = t; i < HDn * LLn; i += 256) lt_s[i] = lt[h * HDn * LLn + i];
  if (t < HDn) qe_s[t] = qe[h * HDn + t];
  if (t < LLn) { lb_s[t] = lb[h * LLn + t]; rpb_s[t] = rpb[h * LLn + t]; }
  __syncthreads();

  const size_t rowq = ((size_t)b * Nn + n) * Cn + h * HDn;
  float qs[HDn];
  #pragma unroll
  for (int dq = 0; dq < 8; ++dq) {
    float4 s4 = ((const float4*)(qs_ + rowq))[dq];
    qs[dq*4]=s4.x; qs[dq*4+1]=s4.y; qs[dq*4+2]=s4.z; qs[dq*4+3]=s4.w;
  }
  float ssq = 0.f;
  #pragma unroll
  for (int d = 0; d < HDn; ++d) ssq += qs[d] * qs[d];
  const float M = sqrtf(ssq) + scal[0];

  float acc[HDn];
  #pragma unroll
  for (int d = 0; d < HDn; ++d) acc[d] = 0.f;
  float l_run = 0.f;

  const float* kbase = kpn + (size_t)bh * PLn * HDn;
  const float* vbase = vpl + (size_t)bh * PLn * HDn;
  const unsigned short* bptr = bias2 + (size_t)h * PLn * Nn + n;

  const int m0 = w * 49;
  #pragma unroll 2
  for (int i = 0; i < 49; ++i) {
    const int m = m0 + i;
    const float bias = b2f(bptr[(size_t)m * Nn]);
    const float4* k4 = (const float4*)(kbase + m * HDn);   // wave-uniform
    float p0=0,p1=0,p2=0,p3=0;
    #pragma unroll
    for (int dq = 0; dq < 8; ++dq) {
      float4 kk = k4[dq];
      p0 += qs[dq*4+0]*kk.x; p1 += qs[dq*4+1]*kk.y;
      p2 += qs[dq*4+2]*kk.z; p3 += qs[dq*4+3]*kk.w;
    }
    const float p = __expf(((p0+p1)+(p2+p3) + bias) - M);
    l_run += p;
    const float4* v4 = (const float4*)(vbase + m * HDn);   // wave-uniform
    #pragma unroll
    for (int dq = 0; dq < 8; ++dq) {
      float4 vv = v4[dq];
      const int d = dq*4;
      acc[d] += p*vv.x; acc[d+1] += p*vv.y; acc[d+2] += p*vv.z; acc[d+3] += p*vv.w;
    }
  }

  // local part: wave w handles lc = w, w+4, w+8
  float ext[HDn];
  #pragma unroll
  for (int d = 0; d < HDn; ++d) ext[d] = 0.f;
  const float spt = log1pf(__expf(temp[h]));
  const float inv_qs = 1.f / (spt * slsp[n]);
  const int pi = n / Wn, pj = n % Wn;
  for (int lc = w; lc < LLn; lc += 4) {
    const int ii = pi + lc/3 - 1, jj = pj + (lc%3) - 1;
    if (ii < 0 || ii >= Hh || jj < 0 || jj >= Wn) continue;
    const int nb2 = ii * Wn + jj;
    float e = lb_s[lc];
    #pragma unroll
    for (int d = 0; d < HDn; ++d) e += (qs[d]*inv_qs - qe_s[d]) * lt_s[d*LLn + lc];
    const float* kr = fused + ((size_t)b * Nn + nb2) * 1024 + 256 + h * HDn;
    float p0=0,p1=0,p2=0,p3=0;
    #pragma unroll
    for (int dq = 0; dq < 8; ++dq) {
      float4 kk = ((const float4*)kr)[dq];
      p0 += qs[dq*4+0]*kk.x; p1 += qs[dq*4+1]*kk.y;
      p2 += qs[dq*4+2]*kk.z; p3 += qs[dq*4+3]*kk.w;
    }
    const float p = __expf(((p0+p1)+(p2+p3) + rpb_s[lc]) - M);
    l_run += p;
    #pragma unroll
    for (int dq = 0; dq < 8; ++dq) {              // reload v (keeps VGPR low)
      float4 vv = ((const float4*)(kr + Cn))[dq];
      const int d = dq*4;
      acc[d] += p*vv.x; acc[d+1] += p*vv.y; acc[d+2] += p*vv.z; acc[d+3] += p*vv.w;
      ext[d] += e*vv.x; ext[d+1] += e*vv.y; ext[d+2] += e*vv.z; ext[d+3] += e*vv.w;
    }
  }

  // phase A: acc + l_run
  float* myred = red + (w * 64 + lane) * 33;
  #pragma unroll
  for (int d = 0; d < HDn; ++d) myred[d] = acc[d];
  myred[32] = l_run;
  __syncthreads();
  const int n2 = t >> 2, dg = t & 3;
  float o[8], l_tot;
  {
    const float* r0 = red + n2 * 33, *r1 = r0 + 64*33, *r2 = r1 + 64*33, *r3 = r2 + 64*33;
    l_tot = r0[32] + r1[32] + r2[32] + r3[32];
    #pragma unroll
    for (int j = 0; j < 8; ++j)
      o[j] = r0[dg*8+j] + r1[dg*8+j] + r2[dg*8+j] + r3[dg*8+j];
  }
  __syncthreads();
  // phase B: ext
  #pragma unroll
  for (int d = 0; d < HDn; ++d) myred[d] = ext[d];
  __syncthreads();
  float et[8];
  {
    const float* r0 = red + n2 * 33, *r1 = r0 + 64*33, *r2 = r1 + 64*33, *r3 = r2 + 64*33;
    #pragma unroll
    for (int j = 0; j < 8; ++j)
      et[j] = r0[dg*8+j] + r1[dg*8+j] + r2[dg*8+j] + r3[dg*8+j];
  }
  const float invl = 1.f / l_tot;
  uint4 u;
  u.x = f2b(o[0]*invl+et[0]) | ((unsigned int)f2b(o[1]*invl+et[1]) << 16);
  u.y = f2b(o[2]*invl+et[2]) | ((unsigned int)f2b(o[3]*invl+et[3]) << 16);
  u.z = f2b(o[4]*invl+et[4]) | ((unsigned int)f2b(o[5]*invl+et[5]) << 16);
  u.w = f2b(o[6]*invl+et[6]) | ((unsigned int)f2b(o[7]*invl+et[7]) << 16);
  *(uint4*)(outp + ((size_t)b * Nn + tile*64 + n2) * Cn + h * HDn + dg * 8) = u;
}

// ---------------------------------------------------------------------------
extern "C" void kernel_launch(void* const* d_in, const int* in_sizes, int n_in,
                              void* d_out, int out_size, void* d_ws, size_t ws_size,
                              hipStream_t stream)
{
  const float* x    = (const float*)d_in[0];
  const int*   rpi  = (const int*)d_in[3];
  const float* rct  = (const float*)d_in[4];
  const float* sls  = (const float*)d_in[5];
  const float* q_w  = (const float*)d_in[7];
  const float* q_b  = (const float*)d_in[8];
  const float* kv_w = (const float*)d_in[9];
  const float* kv_b = (const float*)d_in[10];
  const float* sr_w = (const float*)d_in[11];
  const float* sr_b = (const float*)d_in[12];
  const float* ng   = (const float*)d_in[13];
  const float* nbta = (const float*)d_in[14];
  const float* c1w  = (const float*)d_in[15];
  const float* c1b  = (const float*)d_in[16];
  const float* c2w  = (const float*)d_in[17];
  const float* c2b  = (const float*)d_in[18];
  const float* temp = (const float*)d_in[19];
  const float* qe   = (const float*)d_in[20];
  const float* rpb  = (const float*)d_in[21];
  const float* lt   = (const float*)d_in[22];
  const float* lb   = (const float*)d_in[23];
  const float* pw   = (const float*)d_in[24];
  const float* pb   = (const float*)d_in[25];

  float* ws = (float*)d_ws;
  size_t o = 0;
  unsigned short* bf = (unsigned short*)(ws + o); o += TOTCVT / 2;
  float* fused = ws + o;  o += (size_t)Mrows * 1024;
  float* qsb   = ws + o;  o += (size_t)Mrows * Cn;
  float* pln   = ws + o;  o += (size_t)Bn * PLn * Cn;
  float* kvp   = ws + o;  o += (size_t)Bn * PLn * 2 * Cn;
  float* kpn   = ws + o;  o += (size_t)Bn * PLn * Cn;
  float* vpl   = ws + o;  o += (size_t)Bn * PLn * Cn;
  float* tab   = ws + o;  o += (size_t)KTABn * NHn;
  float* scal  = ws + o;  o += 8;
  unsigned short* bias2 = (unsigned short*)(ws + o); o += (size_t)NHn * Nn * PLn / 2;
  unsigned short* outp  = (unsigned short*)(ws + o); o += (size_t)Mrows * Cn / 2;

  const unsigned short* xbf   = bf;
  const unsigned short* qkvsw = bf + QWOFF;
  const unsigned short* pwbf  = bf + PWOFF;

  cvt5<<<TOTCVT/1024, 256, 0, stream>>>(x, q_w, kv_w, sr_w, pw, bf);
  mgemm<1><<<dim3(8, 98), 256, 0, stream>>>(xbf, qkvsw, q_b, kv_b, sr_b, fused, 1024);
  norm_qk2<<<Mrows, 256, 0, stream>>>(fused, qsb, sls, qe, temp);
  pool_ln_k<<<Bn*PLn, 256, 0, stream>>>(fused, pln, ng, nbta);
  gemm_k<<<dim3(8, 13), 256, 0, stream>>>(pln, kv_w, kv_b, kvp, Bn*PLn, 512, 256);
  pool_split_k<<<Bn*PLn, 256, 0, stream>>>(kvp, kpn, vpl);
  cpb_k<<<KTABn, 64, 0, stream>>>(rct, c1w, c1b, c2w, c2b, tab);
  redmax_k<<<1, 256, 0, stream>>>(tab, rpb, scal);
  bias_g_k<<<(Nn*PLn)/256, 256, 0, stream>>>(rpi, tab, bias2);
  attn5<<<dim3(49, NHn, Bn), 256, 0, stream>>>(qsb, sls, temp, qe, lt, lb, fused,
                                               kpn, vpl, bias2, rpb, scal, outp);
  mgemm<0><<<dim3(2, 98), 256, 0, stream>>>(outp, pwbf, pb, pb, pb, (float*)d_out, 256);
}

// Round 8
// 299.397 us; speedup vs baseline: 1.5841x; 1.3403x over previous
//
#include <hip/hip_runtime.h>
#include <hip/hip_bf16.h>
#include <math.h>

#define Bn   4
#define Hh   56
#define Wn   56
#define Cn   256
#define NHn  8
#define HDn  32
#define Nn   3136
#define LLn  9
#define PLn  196
#define PWn  14
#define KTABn 2048
#define Mrows 12544
#define MP   224            // padded pool-key count (14 x 16)

// cvt5 segment offsets (elements)
#define XCNT   3211264
#define QWOFF  XCNT
#define KVWOFF (QWOFF + 65536)
#define SRWOFF (KVWOFF + 131072)
#define PWOFF  (SRWOFF + 65536)
#define TOTCVT (PWOFF + 65536)

typedef __attribute__((ext_vector_type(8))) short short8v;
typedef __attribute__((ext_vector_type(4))) float float4v;

__device__ __forceinline__ unsigned short f2b(float f) {
  __hip_bfloat16 h = __float2bfloat16(f);
  return *(unsigned short*)&h;
}
__device__ __forceinline__ float b2f(unsigned short u) {
  union { unsigned int i; float f; } x; x.i = ((unsigned int)u) << 16; return x.f;
}

// ---------------------------------------------------------------------------
// Convert x + q_w + kv_w + sr_w + proj_w to one contiguous bf16 area.
// ---------------------------------------------------------------------------
__launch_bounds__(256)
__global__ void cvt5(const float* __restrict__ x, const float* __restrict__ qw,
                     const float* __restrict__ kvw, const float* __restrict__ srw,
                     const float* __restrict__ pw, unsigned short* __restrict__ dst)
{
  const int i = (blockIdx.x * 256 + threadIdx.x) * 4;
  const float* src; int off;
  if      (i < XCNT)   { src = x;   off = 0; }
  else if (i < KVWOFF) { src = qw;  off = QWOFF; }
  else if (i < SRWOFF) { src = kvw; off = KVWOFF; }
  else if (i < PWOFF)  { src = srw; off = SRWOFF; }
  else                 { src = pw;  off = PWOFF; }
  const float4 v = *(const float4*)(src + (i - off));
  ushort4 o2;
  o2.x = f2b(v.x); o2.y = f2b(v.y); o2.z = f2b(v.z); o2.w = f2b(v.w);
  *(ushort4*)(dst + i) = o2;
}

// ---------------------------------------------------------------------------
// bf16 MFMA GEMM (unchanged from round 7)
// ---------------------------------------------------------------------------
template <int MODE>
__launch_bounds__(256)
__global__ void mgemm(const unsigned short* __restrict__ A,
                      const unsigned short* __restrict__ Wb,
                      const float* __restrict__ b0, const float* __restrict__ b1,
                      const float* __restrict__ b2, float* __restrict__ C, int Nc)
{
  __shared__ unsigned short As[128 * 64];
  __shared__ unsigned short Bs[128 * 64];
  const int t = threadIdx.x;
  const int w = t >> 6, lane = t & 63;
  const int q = lane >> 4, ln = lane & 15;
  const int n0 = blockIdx.x * 128, m0 = blockIdx.y * 128;
  const int wm = (w >> 1) * 64, wn = (w & 1) * 64;

  float4v acc[4][4];
  #pragma unroll
  for (int mt = 0; mt < 4; ++mt)
    #pragma unroll
    for (int nt = 0; nt < 4; ++nt)
      acc[mt][nt] = (float4v){0.f, 0.f, 0.f, 0.f};

  for (int k0 = 0; k0 < 256; k0 += 64) {
    #pragma unroll
    for (int j = 0; j < 4; ++j) {
      const int u = t + 256 * j;
      const int r = u >> 3, cg = u & 7;
      const int cs = cg ^ (r & 7);
      const uint4 av = *(const uint4*)(A  + (size_t)(m0 + r) * 256 + k0 + cg * 8);
      *(uint4*)(As + r * 64 + cs * 8) = av;
      const uint4 bv = *(const uint4*)(Wb + (size_t)(n0 + r) * 256 + k0 + cg * 8);
      *(uint4*)(Bs + r * 64 + cs * 8) = bv;
    }
    __syncthreads();
    #pragma unroll
    for (int kk = 0; kk < 2; ++kk) {
      short8v af[4], bfr[4];
      const int cg = kk * 4 + q;
      #pragma unroll
      for (int mt = 0; mt < 4; ++mt) {
        const int r = wm + mt * 16 + ln;
        af[mt] = *(const short8v*)(As + r * 64 + (cg ^ (r & 7)) * 8);
      }
      #pragma unroll
      for (int nt = 0; nt < 4; ++nt) {
        const int r = wn + nt * 16 + ln;
        bfr[nt] = *(const short8v*)(Bs + r * 64 + (cg ^ (r & 7)) * 8);
      }
      #pragma unroll
      for (int mt = 0; mt < 4; ++mt)
        #pragma unroll
        for (int nt = 0; nt < 4; ++nt)
          acc[mt][nt] = __builtin_amdgcn_mfma_f32_16x16x32_bf16(af[mt], bfr[nt], acc[mt][nt], 0, 0, 0);
    }
    __syncthreads();
  }

  #pragma unroll
  for (int nt = 0; nt < 4; ++nt) {
    const int col = n0 + wn + nt * 16 + ln;
    float bias;
    if constexpr (MODE == 0) bias = b0[col];
    else {
      const int seg = col >> 8;
      bias = (seg == 0) ? b0[col] : (seg == 3 ? b2[col - 768] : b1[col - 256]);
    }
    #pragma unroll
    for (int mt = 0; mt < 4; ++mt) {
      #pragma unroll
      for (int r = 0; r < 4; ++r) {
        const int row = m0 + wm + mt * 16 + q * 4 + r;
        float v = acc[mt][nt][r] + bias;
        if constexpr (MODE == 1)
          if (col >= 768) v = 0.5f * v * (1.0f + erff(v * 0.70710678118654752f));
        C[(size_t)row * Nc + col] = v;
      }
    }
  }
}

// ---------------------------------------------------------------------------
// fp32 tiled GEMM (pool path only)
// ---------------------------------------------------------------------------
__launch_bounds__(256)
__global__ void gemm_k(const float* __restrict__ A, const float* __restrict__ W,
                       const float* __restrict__ bias, float* __restrict__ Co,
                       int Mr, int Nc, int K)
{
  __shared__ __align__(16) float As[16][64];
  __shared__ __align__(16) float Ws[16][64];
  const int t  = threadIdx.x;
  const int m0 = blockIdx.y * 64, n0 = blockIdx.x * 64;
  const int lm = t >> 2, lk = (t & 3) << 2;
  const int tx = t & 15, ty = t >> 4;
  float acc[4][4] = {};
  int arow = m0 + lm; if (arow >= Mr) arow = Mr - 1;
  const int wrow = n0 + lm;
  for (int k0 = 0; k0 < K; k0 += 16) {
    float4 av = *(const float4*)(A + (size_t)arow * K + k0 + lk);
    As[lk+0][lm] = av.x; As[lk+1][lm] = av.y; As[lk+2][lm] = av.z; As[lk+3][lm] = av.w;
    float4 wv = *(const float4*)(W + (size_t)wrow * K + k0 + lk);
    Ws[lk+0][lm] = wv.x; Ws[lk+1][lm] = wv.y; Ws[lk+2][lm] = wv.z; Ws[lk+3][lm] = wv.w;
    __syncthreads();
    #pragma unroll
    for (int k = 0; k < 16; ++k) {
      float4 a = *(const float4*)&As[k][ty << 2];
      float4 w = *(const float4*)&Ws[k][tx << 2];
      acc[0][0] += a.x*w.x; acc[0][1] += a.x*w.y; acc[0][2] += a.x*w.z; acc[0][3] += a.x*w.w;
      acc[1][0] += a.y*w.x; acc[1][1] += a.y*w.y; acc[1][2] += a.y*w.z; acc[1][3] += a.y*w.w;
      acc[2][0] += a.z*w.x; acc[2][1] += a.z*w.y; acc[2][2] += a.z*w.z; acc[2][3] += a.z*w.w;
      acc[3][0] += a.w*w.x; acc[3][1] += a.w*w.y; acc[3][2] += a.w*w.z; acc[3][3] += a.w*w.w;
    }
    __syncthreads();
  }
  #pragma unroll
  for (int i = 0; i < 4; ++i) {
    const int row = m0 + (ty << 2) + i;
    if (row >= Mr) continue;
    #pragma unroll
    for (int j = 0; j < 4; ++j) {
      const int col = n0 + (tx << 2) + j;
      Co[(size_t)row * Nc + col] = acc[i][j] + bias[col];
    }
  }
}

// ---------------------------------------------------------------------------
// Per-head L2 norm: q -> q_scaled (fp32) ; Mq[b][h][n] = ||qs|| ; k normed.
// ---------------------------------------------------------------------------
__launch_bounds__(256)
__global__ void norm_qk2(float* __restrict__ fused, float* __restrict__ qsb,
                         float* __restrict__ Mq, const float* __restrict__ sls,
                         const float* __restrict__ qe, const float* __restrict__ temp)
{
  const int row = blockIdx.x;            // b*Nn + n
  const int c = threadIdx.x;
  const int h = c >> 5;
  const int b = row / Nn, n = row % Nn;
  float* f = fused + (size_t)row * 1024;
  float qv = f[c];
  float ss = qv * qv;
  #pragma unroll
  for (int m = 16; m >= 1; m >>= 1) ss += __shfl_xor(ss, m);
  const float qn = qv / fmaxf(sqrtf(ss), 1e-12f);
  const float spt = log1pf(expf(temp[h]));
  const float qsv = (qn + qe[c]) * spt * sls[n];
  qsb[(size_t)row * Cn + c] = qsv;
  float m2 = qsv * qsv;
  #pragma unroll
  for (int m = 16; m >= 1; m >>= 1) m2 += __shfl_xor(m2, m);
  if ((c & 31) == 0) Mq[((size_t)(b * NHn + h)) * Nn + n] = sqrtf(m2);
  float kval = f[256 + c];
  float ks = kval * kval;
  #pragma unroll
  for (int m = 16; m >= 1; m >>= 1) ks += __shfl_xor(ks, m);
  f[256 + c] = kval / fmaxf(sqrtf(ks), 1e-12f);
}

// ---------------------------------------------------------------------------
// 4x4 average pool of gelu'd sr + LayerNorm over C
// ---------------------------------------------------------------------------
__launch_bounds__(256)
__global__ void pool_ln_k(const float* __restrict__ fused, float* __restrict__ pln,
                          const float* __restrict__ g, const float* __restrict__ bb)
{
  const int blk = blockIdx.x;
  const int b = blk / PLn, pc = blk % PLn;
  const int pi = pc / PWn, pj = pc % PWn;
  const int c = threadIdx.x;
  float s = 0.f;
  #pragma unroll
  for (int r = 0; r < 4; ++r)
    #pragma unroll
    for (int cc = 0; cc < 4; ++cc) {
      const int n = (pi*4 + r) * Wn + pj*4 + cc;
      s += fused[((size_t)b * Nn + n) * 1024 + 768 + c];
    }
  s *= (1.f/16.f);
  float sum = s, sq = s*s;
  #pragma unroll
  for (int m = 32; m >= 1; m >>= 1) { sum += __shfl_xor(sum, m); sq += __shfl_xor(sq, m); }
  __shared__ float sm[8];
  const int lane = c & 63, wid = c >> 6;
  if (lane == 0) { sm[wid] = sum; sm[4+wid] = sq; }
  __syncthreads();
  const float tot  = sm[0]+sm[1]+sm[2]+sm[3];
  const float totq = sm[4]+sm[5]+sm[6]+sm[7];
  const float mu  = tot * (1.f/256.f);
  const float var = totq * (1.f/256.f) - mu*mu;
  pln[(size_t)blk * Cn + c] = (s - mu) / sqrtf(var + 1e-5f) * g[c] + bb[c];
}

// ---------------------------------------------------------------------------
// pool_pack: kvp -> kbf [bh][224 m][32 d] bf16 (L2-normed k, zero pad m>=196)
//            and vbf [bh][33 d][224 m] bf16 (v transposed; row 32 = ones)
// one block per (b,h); 256 thr = 8 m x 32 d
// ---------------------------------------------------------------------------
__launch_bounds__(256)
__global__ void pool_pack(const float* __restrict__ kvp, unsigned short* __restrict__ kbf,
                          unsigned short* __restrict__ vbf)
{
  const int bh = blockIdx.x;
  const int b = bh >> 3, h = bh & 7;
  const int t = threadIdx.x, mg = t >> 5, d = t & 31;
  for (int mi = 0; mi < MP/8; ++mi) {
    const int m = mi * 8 + mg;
    float kv2 = 0.f, vv = 0.f;
    if (m < PLn) {
      kv2 = kvp[((size_t)(b * PLn + m)) * 512 + h * HDn + d];
      vv  = kvp[((size_t)(b * PLn + m)) * 512 + 256 + h * HDn + d];
    }
    float ssn = kv2 * kv2;
    #pragma unroll
    for (int mm = 16; mm >= 1; mm >>= 1) ssn += __shfl_xor(ssn, mm);
    const float kn = (m < PLn) ? kv2 / fmaxf(sqrtf(ssn), 1e-12f) : 0.f;
    kbf[((size_t)bh * MP + m) * HDn + d] = f2b(kn);
    vbf[((size_t)bh * 33 + d) * MP + m] = f2b(vv);
  }
  for (int i = t; i < MP; i += 256)
    vbf[((size_t)bh * 33 + 32) * MP + i] = f2b(1.0f);
}

// ---------------------------------------------------------------------------
// CPB MLP
// ---------------------------------------------------------------------------
__launch_bounds__(64)
__global__ void cpb_k(const float* __restrict__ rct, const float* __restrict__ w1,
                      const float* __restrict__ b1, const float* __restrict__ w2,
                      const float* __restrict__ b2, float* __restrict__ tab)
{
  const int r = blockIdx.x, t = threadIdx.x;
  const float c0 = rct[r*2], c1 = rct[r*2+1];
  float part[8] = {};
  #pragma unroll
  for (int jj = 0; jj < 8; ++jj) {
    const int j = t * 8 + jj;
    float hv = fmaxf(c0 * w1[j*2] + c1 * w1[j*2+1] + b1[j], 0.f);
    #pragma unroll
    for (int h = 0; h < 8; ++h) part[h] += hv * w2[h*512 + j];
  }
  #pragma unroll
  for (int h = 0; h < 8; ++h)
    for (int mm = 32; mm >= 1; mm >>= 1) part[h] += __shfl_xor(part[h], mm);
  if (t < 8) tab[r*8 + t] = part[t] + b2[t];
}

// ---------------------------------------------------------------------------
// global max over tab and rpb -> scal[0]
// ---------------------------------------------------------------------------
__launch_bounds__(256)
__global__ void redmax_k(const float* __restrict__ tab, const float* __restrict__ rpb,
                         float* __restrict__ scal)
{
  float mx = -1e30f;
  for (int i = threadIdx.x; i < KTABn*NHn; i += 256) mx = fmaxf(mx, tab[i]);
  if (threadIdx.x < NHn*LLn) mx = fmaxf(mx, rpb[threadIdx.x]);
  #pragma unroll
  for (int m = 32; m >= 1; m >>= 1) mx = fmaxf(mx, __shfl_xor(mx, m));
  __shared__ float sm[4];
  if ((threadIdx.x & 63) == 0) sm[threadIdx.x >> 6] = mx;
  __syncthreads();
  if (threadIdx.x == 0) scal[0] = fmaxf(fmaxf(sm[0], sm[1]), fmaxf(sm[2], sm[3]));
}

// ---------------------------------------------------------------------------
// bias_g2: bias2[h][n][224] bf16 = tab[rpi[n][m]][h] ; m>=196 -> -inf
// ---------------------------------------------------------------------------
__launch_bounds__(256)
__global__ void bias_g2(const int* __restrict__ rpi, const float* __restrict__ tab,
                        unsigned short* __restrict__ bias2)
{
  const int tid = blockIdx.x * 256 + threadIdx.x;   // n*224+m ; grid 2744 exact
  const int n = tid / MP, m = tid - n * MP;
  if (m < PLn) {
    const int idx = rpi[(size_t)n * PLn + m];
    #pragma unroll
    for (int h = 0; h < NHn; ++h)
      bias2[((size_t)h * Nn + n) * MP + m] = f2b(tab[(size_t)idx * NHn + h]);
  } else {
    #pragma unroll
    for (int h = 0; h < NHn; ++h)
      bias2[((size_t)h * Nn + n) * MP + m] = 0xFF80;   // bf16 -inf
  }
}

// ---------------------------------------------------------------------------
// attn_pool: flash-style pool attention via MFMA. Block = 64 q-rows, 4 waves
// of 16 rows each, all 224 (padded) keys. Fixed-M softmax (additive partials).
// Writes opart[bh][n][33] = (acc[32], l).
// ---------------------------------------------------------------------------
__launch_bounds__(256)
__global__ void attn_pool(const float* __restrict__ qsb,
                          const unsigned short* __restrict__ kbf,
                          const unsigned short* __restrict__ vbf,
                          const unsigned short* __restrict__ bias2,
                          const float* __restrict__ Mq, const float* __restrict__ scal,
                          float* __restrict__ opart)
{
  __shared__ __align__(16) unsigned short sh[32256];   // 63 KB
  unsigned short* k_lds = sh;              // [224][32]
  unsigned short* v_lds = sh + 7168;       // [48][224] (rows 33-47 unstaged/unused)
  unsigned short* p_lds = sh + 17920;      // 4 strips of [16][224]
  const int t = threadIdx.x;
  const int w = t >> 6, lane = t & 63;
  const int ln = lane & 15, quad = lane >> 4;
  const int tile = blockIdx.x, h = blockIdx.y, b = blockIdx.z;
  const int bh = b * NHn + h;

  {
    const uint4* gk = (const uint4*)(kbf + (size_t)bh * (MP * HDn));
    uint4* lk = (uint4*)k_lds;
    for (int i = t; i < 896; i += 256) lk[i] = gk[i];
    const uint4* gv = (const uint4*)(vbf + (size_t)bh * (33 * MP));
    uint4* lv = (uint4*)v_lds;
    for (int i = t; i < 924; i += 256) lv[i] = gv[i];
  }
  __syncthreads();

  // A-frag: q rows nb..nb+15 (row = lane&15, k = quad*8+j), cvt fp32->bf16
  const int nb = tile * 64 + w * 16;
  short8v afrag;
  {
    const float* qr = qsb + ((size_t)(b * Nn + nb + ln)) * Cn + h * HDn + quad * 8;
    float4 a0 = ((const float4*)qr)[0];
    float4 a1 = ((const float4*)qr)[1];
    afrag[0] = (short)f2b(a0.x); afrag[1] = (short)f2b(a0.y);
    afrag[2] = (short)f2b(a0.z); afrag[3] = (short)f2b(a0.w);
    afrag[4] = (short)f2b(a1.x); afrag[5] = (short)f2b(a1.y);
    afrag[6] = (short)f2b(a1.z); afrag[7] = (short)f2b(a1.w);
  }
  float M4[4];
  const float sc = scal[0];
  #pragma unroll
  for (int r = 0; r < 4; ++r) M4[r] = Mq[(size_t)bh * Nn + nb + quad * 4 + r] + sc;

  // S = Qs.Kp^T, +bias, exp, -> P strip in LDS (bf16, [16 q][224 m])
  unsigned short* pst = p_lds + w * (16 * MP);
  #pragma unroll
  for (int mt = 0; mt < 14; ++mt) {
    short8v bfrag = *(const short8v*)(k_lds + (mt * 16 + ln) * HDn + quad * 8);
    float4v s = __builtin_amdgcn_mfma_f32_16x16x32_bf16(afrag, bfrag,
                                                        (float4v){0.f,0.f,0.f,0.f}, 0, 0, 0);
    #pragma unroll
    for (int r = 0; r < 4; ++r) {
      const int nr = nb + quad * 4 + r;
      const float bv = b2f(bias2[((size_t)h * Nn + nr) * MP + mt * 16 + ln]);
      const float p = __expf(s[r] + bv - M4[r]);
      pst[(quad * 4 + r) * MP + mt * 16 + ln] = f2b(p);
    }
  }
  // P strip is wave-private: no barrier needed (compiler orders ds ops via lgkmcnt)

  // O = P.V  (V cols: 0-31 = d, 32 = ones -> l)
  float4v accO[3];
  accO[0] = (float4v){0.f,0.f,0.f,0.f};
  accO[1] = (float4v){0.f,0.f,0.f,0.f};
  accO[2] = (float4v){0.f,0.f,0.f,0.f};
  #pragma unroll
  for (int kc = 0; kc < 7; ++kc) {
    short8v pa = *(const short8v*)(pst + ln * MP + kc * 32 + quad * 8);
    #pragma unroll
    for (int nt = 0; nt < 3; ++nt) {
      short8v vb = *(const short8v*)(v_lds + (nt * 16 + ln) * MP + kc * 32 + quad * 8);
      accO[nt] = __builtin_amdgcn_mfma_f32_16x16x32_bf16(pa, vb, accO[nt], 0, 0, 0);
    }
  }
  #pragma unroll
  for (int r = 0; r < 4; ++r) {
    const size_t base = ((size_t)bh * Nn + nb + quad * 4 + r) * 33;
    opart[base + ln]      = accO[0][r];
    opart[base + 16 + ln] = accO[1][r];
    if (ln == 0) opart[base + 32] = accO[2][r];
  }
}

// ---------------------------------------------------------------------------
// attn_loc: 9 local keys (VALU) + cross-wave reduction + combine with opart.
// Same structure as round-7 attn5 minus the pool loop; M from Mq (consistent
// with attn_pool so the softmax partition is exact).
// ---------------------------------------------------------------------------
__launch_bounds__(256, 2)
__global__ void attn_loc(const float* __restrict__ qs_, const float* __restrict__ slsp,
                         const float* __restrict__ temp, const float* __restrict__ qe,
                         const float* __restrict__ lt, const float* __restrict__ lb,
                         const float* __restrict__ fused, const float* __restrict__ rpb,
                         const float* __restrict__ scal, const float* __restrict__ Mq,
                         const float* __restrict__ opart, unsigned short* __restrict__ outp)
{
  __shared__ float red[4 * 64 * 33];
  __shared__ float lt_s[HDn * LLn];
  __shared__ float qe_s[HDn];
  __shared__ float lb_s[LLn], rpb_s[LLn];
  const int t = threadIdx.x;
  const int w = t >> 6, lane = t & 63;
  const int tile = blockIdx.x, h = blockIdx.y, b = blockIdx.z;
  const int n = tile * 64 + lane;
  const int bh = b * NHn + h;

  for (int i = t; i < HDn * LLn; i += 256) lt_s[i] = lt[h * HDn * LLn + i];
  if (t < HDn) qe_s[t] = qe[h * HDn + t];
  if (t < LLn) { lb_s[t] = lb[h * LLn + t]; rpb_s[t] = rpb[h * LLn + t]; }
  __syncthreads();

  const size_t rowq = ((size_t)b * Nn + n) * Cn + h * HDn;
  float qs[HDn];
  #pragma unroll
  for (int dq = 0; dq < 8; ++dq) {
    float4 s4 = ((const float4*)(qs_ + rowq))[dq];
    qs[dq*4]=s4.x; qs[dq*4+1]=s4.y; qs[dq*4+2]=s4.z; qs[dq*4+3]=s4.w;
  }
  const float M = Mq[(size_t)bh * Nn + n] + scal[0];

  float acc[HDn], ext[HDn];
  #pragma unroll
  for (int d = 0; d < HDn; ++d) { acc[d] = 0.f; ext[d] = 0.f; }
  float l_run = 0.f;

  const float spt = log1pf(__expf(temp[h]));
  const float inv_qs = 1.f / (spt * slsp[n]);
  const int pi = n / Wn, pj = n % Wn;
  for (int lc = w; lc < LLn; lc += 4) {
    const int ii = pi + lc/3 - 1, jj = pj + (lc%3) - 1;
    if (ii < 0 || ii >= Hh || jj < 0 || jj >= Wn) continue;
    const int nb2 = ii * Wn + jj;
    float e = lb_s[lc];
    #pragma unroll
    for (int d = 0; d < HDn; ++d) e += (qs[d]*inv_qs - qe_s[d]) * lt_s[d*LLn + lc];
    const float* kr = fused + ((size_t)b * Nn + nb2) * 1024 + 256 + h * HDn;
    float p0=0,p1=0,p2=0,p3=0;
    #pragma unroll
    for (int dq = 0; dq < 8; ++dq) {
      float4 kk = ((const float4*)kr)[dq];
      p0 += qs[dq*4+0]*kk.x; p1 += qs[dq*4+1]*kk.y;
      p2 += qs[dq*4+2]*kk.z; p3 += qs[dq*4+3]*kk.w;
    }
    const float p = __expf(((p0+p1)+(p2+p3) + rpb_s[lc]) - M);
    l_run += p;
    #pragma unroll
    for (int dq = 0; dq < 8; ++dq) {
      float4 vv = ((const float4*)(kr + Cn))[dq];
      const int d = dq*4;
      acc[d] += p*vv.x; acc[d+1] += p*vv.y; acc[d+2] += p*vv.z; acc[d+3] += p*vv.w;
      ext[d] += e*vv.x; ext[d+1] += e*vv.y; ext[d+2] += e*vv.z; ext[d+3] += e*vv.w;
    }
  }

  float* myred = red + (w * 64 + lane) * 33;
  #pragma unroll
  for (int d = 0; d < HDn; ++d) myred[d] = acc[d];
  myred[32] = l_run;
  __syncthreads();
  const int n2 = t >> 2, dg = t & 3;
  float o[8], l_tot;
  {
    const float* r0 = red + n2 * 33, *r1 = r0 + 64*33, *r2 = r1 + 64*33, *r3 = r2 + 64*33;
    l_tot = r0[32] + r1[32] + r2[32] + r3[32];
    #pragma unroll
    for (int j = 0; j < 8; ++j)
      o[j] = r0[dg*8+j] + r1[dg*8+j] + r2[dg*8+j] + r3[dg*8+j];
  }
  __syncthreads();
  #pragma unroll
  for (int d = 0; d < HDn; ++d) myred[d] = ext[d];
  __syncthreads();
  float et[8];
  {
    const float* r0 = red + n2 * 33, *r1 = r0 + 64*33, *r2 = r1 + 64*33, *r3 = r2 + 64*33;
    #pragma unroll
    for (int j = 0; j < 8; ++j)
      et[j] = r0[dg*8+j] + r1[dg*8+j] + r2[dg*8+j] + r3[dg*8+j];
  }
  // combine with pool partials
  const size_t obase = ((size_t)bh * Nn + tile * 64 + n2) * 33;
  const float l_pool = opart[obase + 32];
  float op[8];
  #pragma unroll
  for (int j = 0; j < 8; ++j) op[j] = opart[obase + dg * 8 + j];
  const float invl = 1.f / (l_tot + l_pool);
  uint4 u;
  u.x = f2b((o[0]+op[0])*invl+et[0]) | ((unsigned int)f2b((o[1]+op[1])*invl+et[1]) << 16);
  u.y = f2b((o[2]+op[2])*invl+et[2]) | ((unsigned int)f2b((o[3]+op[3])*invl+et[3]) << 16);
  u.z = f2b((o[4]+op[4])*invl+et[4]) | ((unsigned int)f2b((o[5]+op[5])*invl+et[5]) << 16);
  u.w = f2b((o[6]+op[6])*invl+et[6]) | ((unsigned int)f2b((o[7]+op[7])*invl+et[7]) << 16);
  *(uint4*)(outp + ((size_t)b * Nn + tile*64 + n2) * Cn + h * HDn + dg * 8) = u;
}

// ---------------------------------------------------------------------------
extern "C" void kernel_launch(void* const* d_in, const int* in_sizes, int n_in,
                              void* d_out, int out_size, void* d_ws, size_t ws_size,
                              hipStream_t stream)
{
  const float* x    = (const float*)d_in[0];
  const int*   rpi  = (const int*)d_in[3];
  const float* rct  = (const float*)d_in[4];
  const float* sls  = (const float*)d_in[5];
  const float* q_w  = (const float*)d_in[7];
  const float* q_b  = (const float*)d_in[8];
  const float* kv_w = (const float*)d_in[9];
  const float* kv_b = (const float*)d_in[10];
  const float* sr_w = (const float*)d_in[11];
  const float* sr_b = (const float*)d_in[12];
  const float* ng   = (const float*)d_in[13];
  const float* nbta = (const float*)d_in[14];
  const float* c1w  = (const float*)d_in[15];
  const float* c1b  = (const float*)d_in[16];
  const float* c2w  = (const float*)d_in[17];
  const float* c2b  = (const float*)d_in[18];
  const float* temp = (const float*)d_in[19];
  const float* qe   = (const float*)d_in[20];
  const float* rpb  = (const float*)d_in[21];
  const float* lt   = (const float*)d_in[22];
  const float* lb   = (const float*)d_in[23];
  const float* pw   = (const float*)d_in[24];
  const float* pb   = (const float*)d_in[25];

  float* ws = (float*)d_ws;
  size_t o = 0;
  unsigned short* bf = (unsigned short*)(ws + o); o += TOTCVT / 2;
  float* fused = ws + o;  o += (size_t)Mrows * 1024;
  float* qsb   = ws + o;  o += (size_t)Mrows * Cn;
  float* Mq    = ws + o;  o += (size_t)Bn * NHn * Nn;
  float* pln   = ws + o;  o += (size_t)Bn * PLn * Cn;
  float* kvp   = ws + o;  o += (size_t)Bn * PLn * 2 * Cn;
  unsigned short* kbf = (unsigned short*)(ws + o); o += (size_t)Bn * NHn * MP * HDn / 2;
  unsigned short* vbf = (unsigned short*)(ws + o); o += (size_t)Bn * NHn * 33 * MP / 2;
  float* tab   = ws + o;  o += (size_t)KTABn * NHn;
  float* scal  = ws + o;  o += 8;
  unsigned short* bias2 = (unsigned short*)(ws + o); o += (size_t)NHn * Nn * MP / 2;
  float* opart = ws + o;  o += (size_t)Bn * NHn * Nn * 33;
  unsigned short* outp  = (unsigned short*)(ws + o); o += (size_t)Mrows * Cn / 2;

  const unsigned short* xbf   = bf;
  const unsigned short* qkvsw = bf + QWOFF;
  const unsigned short* pwbf  = bf + PWOFF;

  cvt5<<<TOTCVT/1024, 256, 0, stream>>>(x, q_w, kv_w, sr_w, pw, bf);
  mgemm<1><<<dim3(8, 98), 256, 0, stream>>>(xbf, qkvsw, q_b, kv_b, sr_b, fused, 1024);
  norm_qk2<<<Mrows, 256, 0, stream>>>(fused, qsb, Mq, sls, qe, temp);
  pool_ln_k<<<Bn*PLn, 256, 0, stream>>>(fused, pln, ng, nbta);
  gemm_k<<<dim3(8, 13), 256, 0, stream>>>(pln, kv_w, kv_b, kvp, Bn*PLn, 512, 256);
  pool_pack<<<Bn*NHn, 256, 0, stream>>>(kvp, kbf, vbf);
  cpb_k<<<KTABn, 64, 0, stream>>>(rct, c1w, c1b, c2w, c2b, tab);
  redmax_k<<<1, 256, 0, stream>>>(tab, rpb, scal);
  bias_g2<<<(Nn*MP)/256, 256, 0, stream>>>(rpi, tab, bias2);
  attn_pool<<<dim3(49, NHn, Bn), 256, 0, stream>>>(qsb, kbf, vbf, bias2, Mq, scal, opart);
  attn_loc<<<dim3(49, NHn, Bn), 256, 0, stream>>>(qsb, sls, temp, qe, lt, lb, fused,
                                                  rpb, scal, Mq, opart, outp);
  mgemm<0><<<dim3(2, 98), 256, 0, stream>>>(outp, pwbf, pb, pb, pb, (float*)d_out, 256);
}

// Round 9
// 276.467 us; speedup vs baseline: 1.7155x; 1.0829x over previous
//
#include <hip/hip_runtime.h>
#include <hip/hip_bf16.h>
#include <math.h>

#define Bn   4
#define Hh   56
#define Wn   56
#define Cn   256
#define NHn  8
#define HDn  32
#define Nn   3136
#define LLn  9
#define PLn  196
#define PWn  14
#define KTABn 2048
#define Mrows 12544
#define MP   224            // padded pool-key count (14 x 16)

// cvt5 segment offsets (elements)
#define XCNT   3211264
#define QWOFF  XCNT
#define KVWOFF (QWOFF + 65536)
#define SRWOFF (KVWOFF + 131072)
#define PWOFF  (SRWOFF + 65536)
#define TOTCVT (PWOFF + 65536)

typedef __attribute__((ext_vector_type(8))) short short8v;
typedef __attribute__((ext_vector_type(4))) float float4v;

__device__ __forceinline__ unsigned short f2b(float f) {
  __hip_bfloat16 h = __float2bfloat16(f);
  return *(unsigned short*)&h;
}
__device__ __forceinline__ float b2f(unsigned short u) {
  union { unsigned int i; float f; } x; x.i = ((unsigned int)u) << 16; return x.f;
}
__device__ __forceinline__ void u4_to8f(uint4 u, float* o) {
  o[0]=b2f((unsigned short)(u.x&0xffff)); o[1]=b2f((unsigned short)(u.x>>16));
  o[2]=b2f((unsigned short)(u.y&0xffff)); o[3]=b2f((unsigned short)(u.y>>16));
  o[4]=b2f((unsigned short)(u.z&0xffff)); o[5]=b2f((unsigned short)(u.z>>16));
  o[6]=b2f((unsigned short)(u.w&0xffff)); o[7]=b2f((unsigned short)(u.w>>16));
}

// ---------------------------------------------------------------------------
// Convert x + q_w + kv_w + sr_w + proj_w to one contiguous bf16 area.
// ---------------------------------------------------------------------------
__launch_bounds__(256)
__global__ void cvt5(const float* __restrict__ x, const float* __restrict__ qw,
                     const float* __restrict__ kvw, const float* __restrict__ srw,
                     const float* __restrict__ pw, unsigned short* __restrict__ dst)
{
  const int i = (blockIdx.x * 256 + threadIdx.x) * 4;
  const float* src; int off;
  if      (i < XCNT)   { src = x;   off = 0; }
  else if (i < KVWOFF) { src = qw;  off = QWOFF; }
  else if (i < SRWOFF) { src = kvw; off = KVWOFF; }
  else if (i < PWOFF)  { src = srw; off = SRWOFF; }
  else                 { src = pw;  off = PWOFF; }
  const float4 v = *(const float4*)(src + (i - off));
  ushort4 o2;
  o2.x = f2b(v.x); o2.y = f2b(v.y); o2.z = f2b(v.z); o2.w = f2b(v.w);
  *(ushort4*)(dst + i) = o2;
}

// ---------------------------------------------------------------------------
// bf16 MFMA GEMM.
// MODE 0 (proj): fp32 out, bias b0.
// MODE 1 (QKVS): bf16 out, fused epilogue:
//   seg 0 (cols   0-255): q -> per-head L2 norm -> qs=(qn+qe)*spt*sls ; Mq=||qs||
//   seg 1 (cols 256-511): k -> per-head L2 norm
//   seg 2 (cols 512-767): v  plain
//   seg 3 (cols 768-1023): gelu(sr)
// seg is block-uniform (n0>>8). Head sums via quad-local shfl_xor(1,2,4,8).
// ---------------------------------------------------------------------------
template <int MODE>
__launch_bounds__(256)
__global__ void mgemm(const unsigned short* __restrict__ A,
                      const unsigned short* __restrict__ Wb,
                      const float* __restrict__ b0, const float* __restrict__ b1,
                      const float* __restrict__ b2, void* __restrict__ Cv, int Nc,
                      const float* __restrict__ sls, const float* __restrict__ qe,
                      const float* __restrict__ temp, float* __restrict__ Mq)
{
  __shared__ unsigned short As[128 * 64];
  __shared__ unsigned short Bs[128 * 64];
  const int t = threadIdx.x;
  const int w = t >> 6, lane = t & 63;
  const int q = lane >> 4, ln = lane & 15;
  const int n0 = blockIdx.x * 128, m0 = blockIdx.y * 128;
  const int wm = (w >> 1) * 64, wn = (w & 1) * 64;

  float4v acc[4][4];
  #pragma unroll
  for (int mt = 0; mt < 4; ++mt)
    #pragma unroll
    for (int nt = 0; nt < 4; ++nt)
      acc[mt][nt] = (float4v){0.f, 0.f, 0.f, 0.f};

  for (int k0 = 0; k0 < 256; k0 += 64) {
    #pragma unroll
    for (int j = 0; j < 4; ++j) {
      const int u = t + 256 * j;
      const int r = u >> 3, cg = u & 7;
      const int cs = cg ^ (r & 7);
      const uint4 av = *(const uint4*)(A  + (size_t)(m0 + r) * 256 + k0 + cg * 8);
      *(uint4*)(As + r * 64 + cs * 8) = av;
      const uint4 bv = *(const uint4*)(Wb + (size_t)(n0 + r) * 256 + k0 + cg * 8);
      *(uint4*)(Bs + r * 64 + cs * 8) = bv;
    }
    __syncthreads();
    #pragma unroll
    for (int kk = 0; kk < 2; ++kk) {
      short8v af[4], bfr[4];
      const int cg = kk * 4 + q;
      #pragma unroll
      for (int mt = 0; mt < 4; ++mt) {
        const int r = wm + mt * 16 + ln;
        af[mt] = *(const short8v*)(As + r * 64 + (cg ^ (r & 7)) * 8);
      }
      #pragma unroll
      for (int nt = 0; nt < 4; ++nt) {
        const int r = wn + nt * 16 + ln;
        bfr[nt] = *(const short8v*)(Bs + r * 64 + (cg ^ (r & 7)) * 8);
      }
      #pragma unroll
      for (int mt = 0; mt < 4; ++mt)
        #pragma unroll
        for (int nt = 0; nt < 4; ++nt)
          acc[mt][nt] = __builtin_amdgcn_mfma_f32_16x16x32_bf16(af[mt], bfr[nt], acc[mt][nt], 0, 0, 0);
    }
    __syncthreads();
  }

  if constexpr (MODE == 0) {
    float* C = (float*)Cv;
    #pragma unroll
    for (int nt = 0; nt < 4; ++nt) {
      const int col = n0 + wn + nt * 16 + ln;
      const float bias = b0[col];
      #pragma unroll
      for (int mt = 0; mt < 4; ++mt)
        #pragma unroll
        for (int r = 0; r < 4; ++r) {
          const int row = m0 + wm + mt * 16 + q * 4 + r;
          C[(size_t)row * Nc + col] = acc[mt][nt][r] + bias;
        }
    }
  } else {
    unsigned short* Cb = (unsigned short*)Cv;
    const int seg = n0 >> 8;                 // block-uniform
    const int h0 = (n0 + wn) >> 5, h1 = h0 + 1;  // valid for seg 0 (q)
    float spt0 = 0.f, spt1 = 0.f;
    if (seg == 0) { spt0 = log1pf(__expf(temp[h0])); spt1 = log1pf(__expf(temp[h1])); }
    float bia[4], qev[4];
    #pragma unroll
    for (int nt = 0; nt < 4; ++nt) {
      const int col = n0 + wn + nt * 16 + ln;
      bia[nt] = (seg == 0) ? b0[col] : (seg == 3 ? b2[col - 768] : b1[col - 256]);
      if (seg == 0) qev[nt] = qe[col];
    }
    #pragma unroll
    for (int mt = 0; mt < 4; ++mt) {
      #pragma unroll
      for (int r = 0; r < 4; ++r) {
        const int row = m0 + wm + mt * 16 + q * 4 + r;
        float vals[4];
        #pragma unroll
        for (int nt = 0; nt < 4; ++nt) vals[nt] = acc[mt][nt][r] + bia[nt];
        if (seg == 0) {
          float ss0 = vals[0]*vals[0] + vals[1]*vals[1];
          float ss1 = vals[2]*vals[2] + vals[3]*vals[3];
          #pragma unroll
          for (int mk = 1; mk <= 8; mk <<= 1) { ss0 += __shfl_xor(ss0, mk); ss1 += __shfl_xor(ss1, mk); }
          const float i0 = 1.f / fmaxf(sqrtf(ss0), 1e-12f);
          const float i1 = 1.f / fmaxf(sqrtf(ss1), 1e-12f);
          const int nidx = row % Nn, bb = row / Nn;
          const float sl = sls[nidx];
          float qsv[4];
          #pragma unroll
          for (int nt = 0; nt < 4; ++nt) {
            const float inv = (nt < 2) ? i0 : i1;
            const float sp  = (nt < 2) ? spt0 : spt1;
            qsv[nt] = (vals[nt] * inv + qev[nt]) * sp * sl;
          }
          float t0 = qsv[0]*qsv[0] + qsv[1]*qsv[1];
          float t1 = qsv[2]*qsv[2] + qsv[3]*qsv[3];
          #pragma unroll
          for (int mk = 1; mk <= 8; mk <<= 1) { t0 += __shfl_xor(t0, mk); t1 += __shfl_xor(t1, mk); }
          if (ln == 0) {
            Mq[((size_t)(bb * NHn + h0)) * Nn + nidx] = sqrtf(t0);
            Mq[((size_t)(bb * NHn + h1)) * Nn + nidx] = sqrtf(t1);
          }
          #pragma unroll
          for (int nt = 0; nt < 4; ++nt)
            Cb[(size_t)row * 1024 + n0 + wn + nt*16 + ln] = f2b(qsv[nt]);
        } else if (seg == 1) {
          float ss0 = vals[0]*vals[0] + vals[1]*vals[1];
          float ss1 = vals[2]*vals[2] + vals[3]*vals[3];
          #pragma unroll
          for (int mk = 1; mk <= 8; mk <<= 1) { ss0 += __shfl_xor(ss0, mk); ss1 += __shfl_xor(ss1, mk); }
          const float i0 = 1.f / fmaxf(sqrtf(ss0), 1e-12f);
          const float i1 = 1.f / fmaxf(sqrtf(ss1), 1e-12f);
          #pragma unroll
          for (int nt = 0; nt < 4; ++nt)
            Cb[(size_t)row * 1024 + n0 + wn + nt*16 + ln] = f2b(vals[nt] * ((nt < 2) ? i0 : i1));
        } else if (seg == 2) {
          #pragma unroll
          for (int nt = 0; nt < 4; ++nt)
            Cb[(size_t)row * 1024 + n0 + wn + nt*16 + ln] = f2b(vals[nt]);
        } else {
          #pragma unroll
          for (int nt = 0; nt < 4; ++nt) {
            const float v = vals[nt];
            Cb[(size_t)row * 1024 + n0 + wn + nt*16 + ln] =
              f2b(0.5f * v * (1.0f + erff(v * 0.70710678118654752f)));
          }
        }
      }
    }
  }
}

// ---------------------------------------------------------------------------
// fp32 tiled GEMM (pool path only)
// ---------------------------------------------------------------------------
__launch_bounds__(256)
__global__ void gemm_k(const float* __restrict__ A, const float* __restrict__ W,
                       const float* __restrict__ bias, float* __restrict__ Co,
                       int Mr, int Nc, int K)
{
  __shared__ __align__(16) float As[16][64];
  __shared__ __align__(16) float Ws[16][64];
  const int t  = threadIdx.x;
  const int m0 = blockIdx.y * 64, n0 = blockIdx.x * 64;
  const int lm = t >> 2, lk = (t & 3) << 2;
  const int tx = t & 15, ty = t >> 4;
  float acc[4][4] = {};
  int arow = m0 + lm; if (arow >= Mr) arow = Mr - 1;
  const int wrow = n0 + lm;
  for (int k0 = 0; k0 < K; k0 += 16) {
    float4 av = *(const float4*)(A + (size_t)arow * K + k0 + lk);
    As[lk+0][lm] = av.x; As[lk+1][lm] = av.y; As[lk+2][lm] = av.z; As[lk+3][lm] = av.w;
    float4 wv = *(const float4*)(W + (size_t)wrow * K + k0 + lk);
    Ws[lk+0][lm] = wv.x; Ws[lk+1][lm] = wv.y; Ws[lk+2][lm] = wv.z; Ws[lk+3][lm] = wv.w;
    __syncthreads();
    #pragma unroll
    for (int k = 0; k < 16; ++k) {
      float4 a = *(const float4*)&As[k][ty << 2];
      float4 w = *(const float4*)&Ws[k][tx << 2];
      acc[0][0] += a.x*w.x; acc[0][1] += a.x*w.y; acc[0][2] += a.x*w.z; acc[0][3] += a.x*w.w;
      acc[1][0] += a.y*w.x; acc[1][1] += a.y*w.y; acc[1][2] += a.y*w.z; acc[1][3] += a.y*w.w;
      acc[2][0] += a.z*w.x; acc[2][1] += a.z*w.y; acc[2][2] += a.z*w.z; acc[2][3] += a.z*w.w;
      acc[3][0] += a.w*w.x; acc[3][1] += a.w*w.y; acc[3][2] += a.w*w.z; acc[3][3] += a.w*w.w;
    }
    __syncthreads();
  }
  #pragma unroll
  for (int i = 0; i < 4; ++i) {
    const int row = m0 + (ty << 2) + i;
    if (row >= Mr) continue;
    #pragma unroll
    for (int j = 0; j < 4; ++j) {
      const int col = n0 + (tx << 2) + j;
      Co[(size_t)row * Nc + col] = acc[i][j] + bias[col];
    }
  }
}

// ---------------------------------------------------------------------------
// 4x4 average pool of gelu'd sr (fused bf16 cols 768..1023) + LayerNorm over C
// ---------------------------------------------------------------------------
__launch_bounds__(256)
__global__ void pool_ln_k(const unsigned short* __restrict__ fused, float* __restrict__ pln,
                          const float* __restrict__ g, const float* __restrict__ bb)
{
  const int blk = blockIdx.x;
  const int b = blk / PLn, pc = blk % PLn;
  const int pi = pc / PWn, pj = pc % PWn;
  const int c = threadIdx.x;
  float s = 0.f;
  #pragma unroll
  for (int r = 0; r < 4; ++r)
    #pragma unroll
    for (int cc = 0; cc < 4; ++cc) {
      const int n = (pi*4 + r) * Wn + pj*4 + cc;
      s += b2f(fused[((size_t)b * Nn + n) * 1024 + 768 + c]);
    }
  s *= (1.f/16.f);
  float sum = s, sq = s*s;
  #pragma unroll
  for (int m = 32; m >= 1; m >>= 1) { sum += __shfl_xor(sum, m); sq += __shfl_xor(sq, m); }
  __shared__ float sm[8];
  const int lane = c & 63, wid = c >> 6;
  if (lane == 0) { sm[wid] = sum; sm[4+wid] = sq; }
  __syncthreads();
  const float tot  = sm[0]+sm[1]+sm[2]+sm[3];
  const float totq = sm[4]+sm[5]+sm[6]+sm[7];
  const float mu  = tot * (1.f/256.f);
  const float var = totq * (1.f/256.f) - mu*mu;
  pln[(size_t)blk * Cn + c] = (s - mu) / sqrtf(var + 1e-5f) * g[c] + bb[c];
}

// ---------------------------------------------------------------------------
// pool_pack: kvp -> kbf [bh][224 m][32 d] bf16 (L2-normed k, zero pad m>=196)
//            and vbf [bh][33 d][224 m] bf16 (v transposed; row 32 = ones)
// ---------------------------------------------------------------------------
__launch_bounds__(256)
__global__ void pool_pack(const float* __restrict__ kvp, unsigned short* __restrict__ kbf,
                          unsigned short* __restrict__ vbf)
{
  const int bh = blockIdx.x;
  const int b = bh >> 3, h = bh & 7;
  const int t = threadIdx.x, mg = t >> 5, d = t & 31;
  for (int mi = 0; mi < MP/8; ++mi) {
    const int m = mi * 8 + mg;
    float kv2 = 0.f, vv = 0.f;
    if (m < PLn) {
      kv2 = kvp[((size_t)(b * PLn + m)) * 512 + h * HDn + d];
      vv  = kvp[((size_t)(b * PLn + m)) * 512 + 256 + h * HDn + d];
    }
    float ssn = kv2 * kv2;
    #pragma unroll
    for (int mm = 16; mm >= 1; mm >>= 1) ssn += __shfl_xor(ssn, mm);
    const float kn = (m < PLn) ? kv2 / fmaxf(sqrtf(ssn), 1e-12f) : 0.f;
    kbf[((size_t)bh * MP + m) * HDn + d] = f2b(kn);
    vbf[((size_t)bh * 33 + d) * MP + m] = f2b(vv);
  }
  for (int i = t; i < MP; i += 256)
    vbf[((size_t)bh * 33 + 32) * MP + i] = f2b(1.0f);
}

// ---------------------------------------------------------------------------
// CPB MLP
// ---------------------------------------------------------------------------
__launch_bounds__(64)
__global__ void cpb_k(const float* __restrict__ rct, const float* __restrict__ w1,
                      const float* __restrict__ b1, const float* __restrict__ w2,
                      const float* __restrict__ b2, float* __restrict__ tab)
{
  const int r = blockIdx.x, t = threadIdx.x;
  const float c0 = rct[r*2], c1 = rct[r*2+1];
  float part[8] = {};
  #pragma unroll
  for (int jj = 0; jj < 8; ++jj) {
    const int j = t * 8 + jj;
    float hv = fmaxf(c0 * w1[j*2] + c1 * w1[j*2+1] + b1[j], 0.f);
    #pragma unroll
    for (int h = 0; h < 8; ++h) part[h] += hv * w2[h*512 + j];
  }
  #pragma unroll
  for (int h = 0; h < 8; ++h)
    for (int mm = 32; mm >= 1; mm >>= 1) part[h] += __shfl_xor(part[h], mm);
  if (t < 8) tab[r*8 + t] = part[t] + b2[t];
}

// ---------------------------------------------------------------------------
// global max over tab and rpb -> scal[0]
// ---------------------------------------------------------------------------
__launch_bounds__(256)
__global__ void redmax_k(const float* __restrict__ tab, const float* __restrict__ rpb,
                         float* __restrict__ scal)
{
  float mx = -1e30f;
  for (int i = threadIdx.x; i < KTABn*NHn; i += 256) mx = fmaxf(mx, tab[i]);
  if (threadIdx.x < NHn*LLn) mx = fmaxf(mx, rpb[threadIdx.x]);
  #pragma unroll
  for (int m = 32; m >= 1; m >>= 1) mx = fmaxf(mx, __shfl_xor(mx, m));
  __shared__ float sm[4];
  if ((threadIdx.x & 63) == 0) sm[threadIdx.x >> 6] = mx;
  __syncthreads();
  if (threadIdx.x == 0) scal[0] = fmaxf(fmaxf(sm[0], sm[1]), fmaxf(sm[2], sm[3]));
}

// ---------------------------------------------------------------------------
// bias_g2: bias2[h][n][224] bf16 = tab[rpi[n][m]][h] ; m>=196 -> -inf
// ---------------------------------------------------------------------------
__launch_bounds__(256)
__global__ void bias_g2(const int* __restrict__ rpi, const float* __restrict__ tab,
                        unsigned short* __restrict__ bias2)
{
  const int tid = blockIdx.x * 256 + threadIdx.x;
  const int n = tid / MP, m = tid - n * MP;
  if (m < PLn) {
    const int idx = rpi[(size_t)n * PLn + m];
    #pragma unroll
    for (int h = 0; h < NHn; ++h)
      bias2[((size_t)h * Nn + n) * MP + m] = f2b(tab[(size_t)idx * NHn + h]);
  } else {
    #pragma unroll
    for (int h = 0; h < NHn; ++h)
      bias2[((size_t)h * Nn + n) * MP + m] = 0xFF80;   // bf16 -inf
  }
}

// ---------------------------------------------------------------------------
// attn_pool: flash-style pool attention via MFMA; q read straight as bf16.
// ---------------------------------------------------------------------------
__launch_bounds__(256)
__global__ void attn_pool(const unsigned short* __restrict__ fused,
                          const unsigned short* __restrict__ kbf,
                          const unsigned short* __restrict__ vbf,
                          const unsigned short* __restrict__ bias2,
                          const float* __restrict__ Mq, const float* __restrict__ scal,
                          float* __restrict__ opart)
{
  __shared__ __align__(16) unsigned short sh[32256];
  unsigned short* k_lds = sh;
  unsigned short* v_lds = sh + 7168;
  unsigned short* p_lds = sh + 17920;
  const int t = threadIdx.x;
  const int w = t >> 6, lane = t & 63;
  const int ln = lane & 15, quad = lane >> 4;
  const int tile = blockIdx.x, h = blockIdx.y, b = blockIdx.z;
  const int bh = b * NHn + h;

  {
    const uint4* gk = (const uint4*)(kbf + (size_t)bh * (MP * HDn));
    uint4* lk = (uint4*)k_lds;
    for (int i = t; i < 896; i += 256) lk[i] = gk[i];
    const uint4* gv = (const uint4*)(vbf + (size_t)bh * (33 * MP));
    uint4* lv = (uint4*)v_lds;
    for (int i = t; i < 924; i += 256) lv[i] = gv[i];
  }
  __syncthreads();

  const int nb = tile * 64 + w * 16;
  const short8v afrag = *(const short8v*)(fused +
      ((size_t)(b * Nn + nb + ln)) * 1024 + h * HDn + quad * 8);
  float M4[4];
  const float sc = scal[0];
  #pragma unroll
  for (int r = 0; r < 4; ++r) M4[r] = Mq[(size_t)bh * Nn + nb + quad * 4 + r] + sc;

  unsigned short* pst = p_lds + w * (16 * MP);
  #pragma unroll
  for (int mt = 0; mt < 14; ++mt) {
    short8v bfrag = *(const short8v*)(k_lds + (mt * 16 + ln) * HDn + quad * 8);
    float4v s = __builtin_amdgcn_mfma_f32_16x16x32_bf16(afrag, bfrag,
                                                        (float4v){0.f,0.f,0.f,0.f}, 0, 0, 0);
    #pragma unroll
    for (int r = 0; r < 4; ++r) {
      const int nr = nb + quad * 4 + r;
      const float bv = b2f(bias2[((size_t)h * Nn + nr) * MP + mt * 16 + ln]);
      const float p = __expf(s[r] + bv - M4[r]);
      pst[(quad * 4 + r) * MP + mt * 16 + ln] = f2b(p);
    }
  }

  float4v accO[3];
  accO[0] = (float4v){0.f,0.f,0.f,0.f};
  accO[1] = (float4v){0.f,0.f,0.f,0.f};
  accO[2] = (float4v){0.f,0.f,0.f,0.f};
  #pragma unroll
  for (int kc = 0; kc < 7; ++kc) {
    short8v pa = *(const short8v*)(pst + ln * MP + kc * 32 + quad * 8);
    #pragma unroll
    for (int nt = 0; nt < 3; ++nt) {
      short8v vb = *(const short8v*)(v_lds + (nt * 16 + ln) * MP + kc * 32 + quad * 8);
      accO[nt] = __builtin_amdgcn_mfma_f32_16x16x32_bf16(pa, vb, accO[nt], 0, 0, 0);
    }
  }
  #pragma unroll
  for (int r = 0; r < 4; ++r) {
    const size_t base = ((size_t)bh * Nn + nb + quad * 4 + r) * 33;
    opart[base + ln]      = accO[0][r];
    opart[base + 16 + ln] = accO[1][r];
    if (ln == 0) opart[base + 32] = accO[2][r];
  }
}

// ---------------------------------------------------------------------------
// attn_loc: 9 local keys (bf16 fused) + cross-wave reduction + combine.
// ---------------------------------------------------------------------------
__launch_bounds__(256, 2)
__global__ void attn_loc(const unsigned short* __restrict__ fused,
                         const float* __restrict__ slsp, const float* __restrict__ temp,
                         const float* __restrict__ qe, const float* __restrict__ lt,
                         const float* __restrict__ lb, const float* __restrict__ rpb,
                         const float* __restrict__ scal, const float* __restrict__ Mq,
                         const float* __restrict__ opart, unsigned short* __restrict__ outp)
{
  __shared__ float red[4 * 64 * 33];
  __shared__ float lt_s[HDn * LLn];
  __shared__ float qe_s[HDn];
  __shared__ float lb_s[LLn], rpb_s[LLn];
  const int t = threadIdx.x;
  const int w = t >> 6, lane = t & 63;
  const int tile = blockIdx.x, h = blockIdx.y, b = blockIdx.z;
  const int n = tile * 64 + lane;
  const int bh = b * NHn + h;

  for (int i = t; i < HDn * LLn; i += 256) lt_s[i] = lt[h * HDn * LLn + i];
  if (t < HDn) qe_s[t] = qe[h * HDn + t];
  if (t < LLn) { lb_s[t] = lb[h * LLn + t]; rpb_s[t] = rpb[h * LLn + t]; }
  __syncthreads();

  const unsigned short* qp = fused + ((size_t)(b * Nn + n)) * 1024 + h * HDn;
  float qs[HDn];
  #pragma unroll
  for (int i = 0; i < 4; ++i) u4_to8f(((const uint4*)qp)[i], qs + i * 8);
  const float M = Mq[(size_t)bh * Nn + n] + scal[0];

  float acc[HDn], ext[HDn];
  #pragma unroll
  for (int d = 0; d < HDn; ++d) { acc[d] = 0.f; ext[d] = 0.f; }
  float l_run = 0.f;

  const float spt = log1pf(__expf(temp[h]));
  const float inv_qs = 1.f / (spt * slsp[n]);
  const int pi = n / Wn, pj = n % Wn;
  for (int lc = w; lc < LLn; lc += 4) {
    const int ii = pi + lc/3 - 1, jj = pj + (lc%3) - 1;
    if (ii < 0 || ii >= Hh || jj < 0 || jj >= Wn) continue;
    const int nb2 = ii * Wn + jj;
    float e = lb_s[lc];
    #pragma unroll
    for (int d = 0; d < HDn; ++d) e += (qs[d]*inv_qs - qe_s[d]) * lt_s[d*LLn + lc];
    const unsigned short* kr = fused + ((size_t)(b * Nn + nb2)) * 1024 + 256 + h * HDn;
    float kk[HDn];
    #pragma unroll
    for (int i = 0; i < 4; ++i) u4_to8f(((const uint4*)kr)[i], kk + i * 8);
    float p0=0,p1=0,p2=0,p3=0;
    #pragma unroll
    for (int dq = 0; dq < 8; ++dq) {
      const int d = dq*4;
      p0 += qs[d]*kk[d]; p1 += qs[d+1]*kk[d+1]; p2 += qs[d+2]*kk[d+2]; p3 += qs[d+3]*kk[d+3];
    }
    const float p = __expf(((p0+p1)+(p2+p3) + rpb_s[lc]) - M);
    l_run += p;
    float vv[HDn];
    #pragma unroll
    for (int i = 0; i < 4; ++i) u4_to8f(((const uint4*)(kr + 256))[i], vv + i * 8);
    #pragma unroll
    for (int d = 0; d < HDn; ++d) { acc[d] += p * vv[d]; ext[d] += e * vv[d]; }
  }

  float* myred = red + (w * 64 + lane) * 33;
  #pragma unroll
  for (int d = 0; d < HDn; ++d) myred[d] = acc[d];
  myred[32] = l_run;
  __syncthreads();
  const int n2 = t >> 2, dg = t & 3;
  float o[8], l_tot;
  {
    const float* r0 = red + n2 * 33, *r1 = r0 + 64*33, *r2 = r1 + 64*33, *r3 = r2 + 64*33;
    l_tot = r0[32] + r1[32] + r2[32] + r3[32];
    #pragma unroll
    for (int j = 0; j < 8; ++j)
      o[j] = r0[dg*8+j] + r1[dg*8+j] + r2[dg*8+j] + r3[dg*8+j];
  }
  __syncthreads();
  #pragma unroll
  for (int d = 0; d < HDn; ++d) myred[d] = ext[d];
  __syncthreads();
  float et[8];
  {
    const float* r0 = red + n2 * 33, *r1 = r0 + 64*33, *r2 = r1 + 64*33, *r3 = r2 + 64*33;
    #pragma unroll
    for (int j = 0; j < 8; ++j)
      et[j] = r0[dg*8+j] + r1[dg*8+j] + r2[dg*8+j] + r3[dg*8+j];
  }
  const size_t obase = ((size_t)bh * Nn + tile * 64 + n2) * 33;
  const float l_pool = opart[obase + 32];
  float op[8];
  #pragma unroll
  for (int j = 0; j < 8; ++j) op[j] = opart[obase + dg * 8 + j];
  const float invl = 1.f / (l_tot + l_pool);
  uint4 u;
  u.x = f2b((o[0]+op[0])*invl+et[0]) | ((unsigned int)f2b((o[1]+op[1])*invl+et[1]) << 16);
  u.y = f2b((o[2]+op[2])*invl+et[2]) | ((unsigned int)f2b((o[3]+op[3])*invl+et[3]) << 16);
  u.z = f2b((o[4]+op[4])*invl+et[4]) | ((unsigned int)f2b((o[5]+op[5])*invl+et[5]) << 16);
  u.w = f2b((o[6]+op[6])*invl+et[6]) | ((unsigned int)f2b((o[7]+op[7])*invl+et[7]) << 16);
  *(uint4*)(outp + ((size_t)b * Nn + tile*64 + n2) * Cn + h * HDn + dg * 8) = u;
}

// ---------------------------------------------------------------------------
extern "C" void kernel_launch(void* const* d_in, const int* in_sizes, int n_in,
                              void* d_out, int out_size, void* d_ws, size_t ws_size,
                              hipStream_t stream)
{
  const float* x    = (const float*)d_in[0];
  const int*   rpi  = (const int*)d_in[3];
  const float* rct  = (const float*)d_in[4];
  const float* sls  = (const float*)d_in[5];
  const float* q_w  = (const float*)d_in[7];
  const float* q_b  = (const float*)d_in[8];
  const float* kv_w = (const float*)d_in[9];
  const float* kv_b = (const float*)d_in[10];
  const float* sr_w = (const float*)d_in[11];
  const float* sr_b = (const float*)d_in[12];
  const float* ng   = (const float*)d_in[13];
  const float* nbta = (const float*)d_in[14];
  const float* c1w  = (const float*)d_in[15];
  const float* c1b  = (const float*)d_in[16];
  const float* c2w  = (const float*)d_in[17];
  const float* c2b  = (const float*)d_in[18];
  const float* temp = (const float*)d_in[19];
  const float* qe   = (const float*)d_in[20];
  const float* rpb  = (const float*)d_in[21];
  const float* lt   = (const float*)d_in[22];
  const float* lb   = (const float*)d_in[23];
  const float* pw   = (const float*)d_in[24];
  const float* pb   = (const float*)d_in[25];

  float* ws = (float*)d_ws;
  size_t o = 0;
  unsigned short* bf = (unsigned short*)(ws + o); o += TOTCVT / 2;
  unsigned short* fused = (unsigned short*)(ws + o); o += (size_t)Mrows * 512;  // bf16 [12544][1024]
  float* Mq    = ws + o;  o += (size_t)Bn * NHn * Nn;
  float* pln   = ws + o;  o += (size_t)Bn * PLn * Cn;
  float* kvp   = ws + o;  o += (size_t)Bn * PLn * 2 * Cn;
  unsigned short* kbf = (unsigned short*)(ws + o); o += (size_t)Bn * NHn * MP * HDn / 2;
  unsigned short* vbf = (unsigned short*)(ws + o); o += (size_t)Bn * NHn * 33 * MP / 2;
  float* tab   = ws + o;  o += (size_t)KTABn * NHn;
  float* scal  = ws + o;  o += 8;
  unsigned short* bias2 = (unsigned short*)(ws + o); o += (size_t)NHn * Nn * MP / 2;
  float* opart = ws + o;  o += (size_t)Bn * NHn * Nn * 33;
  unsigned short* outp  = (unsigned short*)(ws + o); o += (size_t)Mrows * Cn / 2;

  const unsigned short* xbf   = bf;
  const unsigned short* qkvsw = bf + QWOFF;
  const unsigned short* pwbf  = bf + PWOFF;

  cvt5<<<TOTCVT/1024, 256, 0, stream>>>(x, q_w, kv_w, sr_w, pw, bf);
  mgemm<1><<<dim3(8, 98), 256, 0, stream>>>(xbf, qkvsw, q_b, kv_b, sr_b, fused, 1024,
                                            sls, qe, temp, Mq);
  pool_ln_k<<<Bn*PLn, 256, 0, stream>>>(fused, pln, ng, nbta);
  gemm_k<<<dim3(8, 13), 256, 0, stream>>>(pln, kv_w, kv_b, kvp, Bn*PLn, 512, 256);
  pool_pack<<<Bn*NHn, 256, 0, stream>>>(kvp, kbf, vbf);
  cpb_k<<<KTABn, 64, 0, stream>>>(rct, c1w, c1b, c2w, c2b, tab);
  redmax_k<<<1, 256, 0, stream>>>(tab, rpb, scal);
  bias_g2<<<(Nn*MP)/256, 256, 0, stream>>>(rpi, tab, bias2);
  attn_pool<<<dim3(49, NHn, Bn), 256, 0, stream>>>(fused, kbf, vbf, bias2, Mq, scal, opart);
  attn_loc<<<dim3(49, NHn, Bn), 256, 0, stream>>>(fused, sls, temp, qe, lt, lb,
                                                  rpb, scal, Mq, opart, outp);
  mgemm<0><<<dim3(2, 98), 256, 0, stream>>>(outp, pwbf, pb, pb, pb, (float*)d_out, 256,
                                            nullptr, nullptr, nullptr, nullptr);
}